// Round 4
// baseline (311.029 us; speedup 1.0000x reference)
//
#include <hip/hip_runtime.h>

// SNN 2048->2048->2048->512, T=100, batch 32, LIF.
// Per layer: big GEMM over all t (M=3200=T*32) + sequential LIF scan.
// 7 stream-ordered launches, no grid sync.
//
// Unified "octet-blocked" layout (pitch MTOT) for spikes AND I:
//   half_idx(v, m) = ((v>>3)*MTOT + m)*8 + (v&7)     v = feature index
// Wave B-frag load at ((kb*4+quad)*MTOT + m0+mi)*8 yields
//   B[k=kb*32+quad*8+j][n=m0+mi]   (proven rounds 6-9).
//
// ws regions (total 39,321,600 B -- PROVEN available in round 7):
//   R0 [0,13107200) | R1 [+13107200) | I [+26214400)
// Schedule: fuse{enc->R0, convW0->R1} | gemm0(R1,R0->I) | fuse{scan0, convW1}
//   | gemm1 | fuse{scan1, convW2} | gemm2 | scan2(I->out)
//
// R13 (theory: LDS-read pipe is top bottleneck -- every wave read the FULL
// 256KB A-tile = 4MB/block = 1GB/kernel = ~20us of ds_read_b128 issue):
//   K-SPLIT WAVE PAIRS: 16 waves = 2 kg x 8 mg. Pair splits K; each wave
//   reads only its 16-kstep slice per half -> A-LDS traffic HALVED.
//   B-L2 unchanged (kg k-slices disjoint). mg owns {4,3,...,3} of the 25
//   m-tiles; each A-frag feeds 12-16 MFMAs (was 4-8). kg=1 writes f32
//   partials to the dead A-LDS buffer (8 x 16KB = 128KB), barrier, kg=0
//   reduces + stores. Staging: simple 2-half barrier-sandwiched
//   global_load_lds (R12 proved drains are cheap; quarter pipeline
//   reverted as neutral). VGPR audit NT=4 path ~124 <= 128 cap.
#define T_STEPS 100
#define MTOT    3200
#define MTOT8   25600
#define R0_OFF  0
#define R1_OFF  13107200
#define I_OFF   26214400

typedef _Float16 half8_t __attribute__((ext_vector_type(8)));
typedef _Float16 half4_t __attribute__((ext_vector_type(4)));
typedef float    f32x4   __attribute__((ext_vector_type(4)));

// ---------------- encode (device fn): Poisson spikes for all t ----------
__device__ __forceinline__ void encode_body(
    int blk, const float* __restrict__ x, const float* __restrict__ noise,
    _Float16* __restrict__ spk0, float* __restrict__ out)
{
    if (blk == 0 && threadIdx.x == 0) out[16384] = 0.0f;  // runs first
    const int tid = threadIdx.x;
    const int m0  = blk * 16;
    __shared__ half8_t lds[16 * 257];    // pad: store-phase reads conflict-free
    #pragma unroll
    for (int ml = 0; ml < 16; ++ml) {    // read phase: thread = feature octet
        const int m = m0 + ml;
        const int t = m >> 5, b = m & 31;
        const float4 x1 = *(const float4*)(x + b * 2048 + tid * 8);
        const float4 x2 = *(const float4*)(x + b * 2048 + tid * 8 + 4);
        const float4 n1 = *(const float4*)(noise + (size_t)t * 65536 + b * 2048 + tid * 8);
        const float4 n2 = *(const float4*)(noise + (size_t)t * 65536 + b * 2048 + tid * 8 + 4);
        const float xr[8] = {x1.x,x1.y,x1.z,x1.w,x2.x,x2.y,x2.z,x2.w};
        const float nz[8] = {n1.x,n1.y,n1.z,n1.w,n2.x,n2.y,n2.z,n2.w};
        half8_t sp;
        #pragma unroll
        for (int j = 0; j < 8; ++j) {
            const float r = fminf(fmaxf(xr[j], 0.0f), 1.0f);
            sp[j] = (nz[j] < r) ? (_Float16)1.0f : (_Float16)0.0f;
        }
        lds[ml * 257 + tid] = sp;
    }
    __syncthreads();
    #pragma unroll
    for (int r = 0; r < 16; ++r) {       // store phase: lanes = consecutive m
        const int ml  = tid & 15;
        const int oct = r * 16 + (tid >> 4);
        *(half8_t*)(spk0 + ((size_t)oct * MTOT + m0 + ml) * 8) = lds[ml * 257 + oct];
    }
}

// ------------- convw (device fn): W fp32 -> fp16 A-frag swizzled ---------
// Wf[(row>>4)*32768 + ((koct>>2)*64 + (koct&3)*16 + (row&15))*8 + j]
//   = W[row][koct*8+j];  8 rows per block.
__device__ __forceinline__ void convw_body(
    int blk, const float* __restrict__ W, _Float16* __restrict__ Wf)
{
    const int koct = threadIdx.x;        // 0..255
    #pragma unroll
    for (int r = 0; r < 8; ++r) {
        const int row = blk * 8 + r;
        const float* wp = W + (size_t)row * 2048 + koct * 8;
        const float4 f1 = *(const float4*)(wp);
        const float4 f2 = *(const float4*)(wp + 4);
        half8_t h = {(_Float16)f1.x,(_Float16)f1.y,(_Float16)f1.z,(_Float16)f1.w,
                     (_Float16)f2.x,(_Float16)f2.y,(_Float16)f2.z,(_Float16)f2.w};
        const size_t idx = (size_t)(row >> 4) * 32768
                         + ((size_t)((koct >> 2) * 64 + (koct & 3) * 16 + (row & 15))) * 8;
        *(half8_t*)(Wf + idx) = h;
    }
}

// ------------- scan (device fn): LIF, sequential t, parallel (n,b) -------
__device__ __forceinline__ void scan_body(
    int blk, const _Float16* __restrict__ I, const float* __restrict__ bias,
    _Float16* __restrict__ spk_out, float* __restrict__ out,
    const int nshift, const int is_last)
{
    const int gid = blk * 256 + threadIdx.x;     // [0, 32<<nshift)
    const int N = 1 << nshift;
    const int n = gid & (N - 1);
    const int b = gid >> nshift;
    const float bi = bias[n];
    const size_t nbase = (size_t)(n >> 3) * (MTOT * 8) + (n & 7);
    float mem = 0.f, syn = 0.f, osum = 0.f, cnt = 0.f;
    #pragma unroll 4
    for (int t = 0; t < T_STEPS; ++t) {
        const int m = t * 32 + b;
        const float Iv = (float)I[nbase + (size_t)m * 8] + bi;
        syn = syn + (-syn / 5.0f + Iv);
        mem = mem + (-mem / 20.0f + syn);
        const float sv = (mem >= 1.0f) ? 1.0f : 0.0f;
        mem = (sv != 0.0f) ? 0.0f : mem;       // reset
        mem = (mem > 0.0f) ? mem : 0.0f;       // clamp negatives
        cnt += sv; osum += sv;
        if (!is_last) spk_out[nbase + (size_t)m * 8] = (_Float16)sv;
    }
    if (is_last) out[b * 512 + n] = osum * 0.01f;    // mean over T
    float c = cnt;
    #pragma unroll
    for (int s2 = 1; s2 < 64; s2 <<= 1) c += __shfl_xor(c, s2);
    if ((threadIdx.x & 63) == 0) atomicAdd(&out[16384], c);
}

// ---------------- fused small kernels (all 256 thr) ----------------
__global__ __launch_bounds__(256, 2) void snn_enc_convw_kernel(
    const float* __restrict__ x, const float* __restrict__ noise,
    _Float16* __restrict__ spk0, float* __restrict__ out,
    const float* __restrict__ W, _Float16* __restrict__ Wf)
{
    if (blockIdx.x < 200) encode_body(blockIdx.x, x, noise, spk0, out);
    else                  convw_body(blockIdx.x - 200, W, Wf);
}

__global__ __launch_bounds__(256, 4) void snn_scan_convw_kernel(
    const _Float16* __restrict__ I, const float* __restrict__ bias,
    _Float16* __restrict__ spk_out, float* __restrict__ out,
    const int scan_blocks, const int nshift,
    const float* __restrict__ W, _Float16* __restrict__ Wf)
{
    if ((int)blockIdx.x < scan_blocks)
        scan_body(blockIdx.x, I, bias, spk_out, out, nshift, 0);
    else
        convw_body(blockIdx.x - scan_blocks, W, Wf);
}

__global__ __launch_bounds__(256, 4) void snn_scan_kernel(
    const _Float16* __restrict__ I, const float* __restrict__ bias,
    float* __restrict__ out, const int nshift)
{
    scan_body(blockIdx.x, I, bias, nullptr, out, nshift, 1);
}

// ============ 64-row K-split GEMM (gemm0/1): I = spk @ W^T ==============
// Block: 64 N-rows, 16 waves = 2 kg x 8 mg, LDS 128 KB = one K-half of A.
// Wave (kg,mg): NT m-tiles (mg==0 -> 4, else 3), ksteps kg*16..kg*16+15 of
// each half. Pair (kg=0,1) covers full K; f32 partial reduction via LDS.
// NC=8, chunk == XCD, jcount = 25 for every chunk (200 = 8*25).

__device__ __forceinline__ half8_t ldBo(
    const _Float16* __restrict__ spk, const int voff, const int kq)
{
    return *(const half8_t*)(spk + (size_t)voff + (size_t)kq * MTOT8);
}

// Stage one 128 KB A-half via global_load_lds (wave-uniform dst base,
// lane-consecutive 16B). 8 instrs/wave. Group s = 16 rows; half h selects
// the group's k-half (16 KB units of 16384 halves).
__device__ __forceinline__ void stage_half(
    const _Float16* __restrict__ Wf, _Float16* __restrict__ wlds,
    const int nbb, const int h, const int w, const int lane)
{
    #pragma unroll
    for (int r = 0; r < 8; ++r) {
        const int unit = r * 1024 + w * 64 + lane;     // 16B units, 0..8191
        const int s = unit >> 11, off = unit & 2047;
        const _Float16* src = Wf + (size_t)(4 * nbb + s) * 32768
                            + (size_t)h * 16384 + (size_t)off * 8;
        _Float16* dst = wlds + (size_t)unit * 8;
        __builtin_amdgcn_global_load_lds(
            (const __attribute__((address_space(1))) void*)src,
            (__attribute__((address_space(3))) void*)dst, 16, 0, 0);
    }
}

// One K-half for one wave: 16 ksteps (local kbl = kg*16 + j). Each j:
// 4 A-frags feed 4*NT MFMAs; reload the used B set <- sequence pos j+2.
// Wave's kstep sequence: p<16 -> kb = H*32 + kg*16 + p ; p>=16 (H==0 only)
// -> kb = 32 + kg*16 + (p-16) = kg*16 + p + 16.
template<int NT, int H>
__device__ __forceinline__ void compute_half(
    const _Float16* __restrict__ wlds, const _Float16* __restrict__ spk,
    const int (&voff)[NT], half8_t (&bE)[NT], half8_t (&bO)[NT],
    f32x4 (&acc)[NT][4], const int lane, const int quad, const int kg)
{
    #pragma unroll
    for (int j = 0; j < 16; ++j) {
        half8_t a[4];
        #pragma unroll
        for (int s = 0; s < 4; ++s)
            a[s] = *(const half8_t*)(wlds + (size_t)s * 16384
                                    + (size_t)((kg * 16 + j) * 64 + lane) * 8);
        if ((j & 1) == 0) {
            #pragma unroll
            for (int t = 0; t < NT; ++t) {
                #pragma unroll
                for (int s = 0; s < 4; ++s)
                    acc[t][s] = __builtin_amdgcn_mfma_f32_16x16x32_f16(a[s], bE[t], acc[t][s], 0, 0, 0);
            }
            if (H == 0 || j + 2 < 16) {   // reload bE <- seq pos j+2
                const int kb = kg * 16 + ((j + 2 < 16) ? (H * 32 + j + 2) : (j + 18));
                const int kq = kb * 4 + quad;
                #pragma unroll
                for (int t = 0; t < NT; ++t) bE[t] = ldBo(spk, voff[t], kq);
            }
        } else {
            #pragma unroll
            for (int t = 0; t < NT; ++t) {
                #pragma unroll
                for (int s = 0; s < 4; ++s)
                    acc[t][s] = __builtin_amdgcn_mfma_f32_16x16x32_f16(a[s], bO[t], acc[t][s], 0, 0, 0);
            }
            if (H == 0 || j + 2 < 16) {   // reload bO <- seq pos j+2
                const int kb = kg * 16 + ((j + 2 < 16) ? (H * 32 + j + 2) : (j + 18));
                const int kq = kb * 4 + quad;
                #pragma unroll
                for (int t = 0; t < NT; ++t) bO[t] = ldBo(spk, voff[t], kq);
            }
        }
    }
}

template<int NT>
__device__ __forceinline__ void gemm64k_run(
    const _Float16* __restrict__ Wf, const _Float16* __restrict__ spk,
    _Float16* __restrict__ I, _Float16* __restrict__ wlds,
    const int chunk, const int nbb, const int jl_start,
    const int w, const int lane, const int quad, const int mi,
    const int kg, const int mg)
{
    const int row_base = nbb * 64;

    int voff[NT];
    #pragma unroll
    for (int t = 0; t < NT; ++t)
        voff[t] = ((chunk + 8 * (jl_start + t)) * 16 + mi) * 8;

    // B preloads (seq pos 0,1) BEFORE staging: complete under the stage
    // drain of the first __syncthreads.
    half8_t bE[NT], bO[NT];
    {
        const int kq0 = (kg * 16) * 4 + quad;
        #pragma unroll
        for (int t = 0; t < NT; ++t) bE[t] = ldBo(spk, voff[t], kq0);
        const int kq1 = kq0 + 4;
        #pragma unroll
        for (int t = 0; t < NT; ++t) bO[t] = ldBo(spk, voff[t], kq1);
    }

    f32x4 acc[NT][4];
    #pragma unroll
    for (int t = 0; t < NT; ++t) {
        #pragma unroll
        for (int s = 0; s < 4; ++s) acc[t][s] = (f32x4){0, 0, 0, 0};
    }

    stage_half(Wf, wlds, nbb, 0, w, lane);
    __syncthreads();
    compute_half<NT, 0>(wlds, spk, voff, bE, bO, acc, lane, quad, kg);
    __syncthreads();
    stage_half(Wf, wlds, nbb, 1, w, lane);
    __syncthreads();
    compute_half<NT, 1>(wlds, spk, voff, bE, bO, acc, lane, quad, kg);
    __syncthreads();

    // Reduction: kg=1 writes partials into the dead A buffer (mg*16KB,
    // slot (t*4+s): 64 lanes x 16B, conflict-free), kg=0 adds + stores.
    f32x4* red = (f32x4*)wlds;
    if (kg == 1) {
        #pragma unroll
        for (int t = 0; t < NT; ++t) {
            #pragma unroll
            for (int s = 0; s < 4; ++s)
                red[(mg * 16 + t * 4 + s) * 64 + lane] = acc[t][s];
        }
    }
    __syncthreads();
    if (kg == 0) {
        #pragma unroll
        for (int t = 0; t < NT; ++t) {
            #pragma unroll
            for (int s = 0; s < 4; ++s)
                acc[t][s] += red[(mg * 16 + t * 4 + s) * 64 + lane];
        }
        // store: C row(n)=quad*4+r within subtile s, col(m) -> octet-blocked I
        #pragma unroll
        for (int s = 0; s < 4; ++s) {
            const int n0 = row_base + s * 16 + quad * 4;
            const size_t obase = (size_t)(n0 >> 3) * (MTOT * 8) + (n0 & 7);
            #pragma unroll
            for (int t = 0; t < NT; ++t) {
                const int mt = chunk + 8 * (jl_start + t);
                half4_t h;
                #pragma unroll
                for (int r = 0; r < 4; ++r) h[r] = (_Float16)acc[t][s][r];
                *(half4_t*)(I + obase + (size_t)(mt * 16 + mi) * 8) = h;
            }
        }
    }
}

__global__ __launch_bounds__(1024, 1) void snn_gemm64k_kernel(
    const _Float16* __restrict__ Wf, const _Float16* __restrict__ spk,
    _Float16* __restrict__ I)
{
    const int tid  = threadIdx.x;
    const int lane = tid & 63;
    const int w    = tid >> 6;            // wave 0..15
    const int mi   = lane & 15;
    const int quad = lane >> 4;
    const int chunk = blockIdx.x & 7;     // == XCD
    const int nbb   = blockIdx.x >> 3;    // 0..31 (64-row groups)
    const int mg = w & 7;                 // m-group
    const int kg = w >> 3;                // k-group (pair index)
    // tiles: mg 0 -> {0,1,2,3}; mg 1..7 -> {3mg+1, 3mg+2, 3mg+3}  (25 total)
    const int jl_start = (mg == 0) ? 0 : (3 * mg + 1);

    __shared__ _Float16 wlds[65536];      // 128 KB: A K-half, then partials

    if (mg == 0)
        gemm64k_run<4>(Wf, spk, I, wlds, chunk, nbb, jl_start, w, lane, quad, mi, kg, mg);
    else
        gemm64k_run<3>(Wf, spk, I, wlds, chunk, nbb, jl_start, w, lane, quad, mi, kg, mg);
}

// ============== 32-row GEMM (gemm2, proven R9 version) ==================
template<int NC, int TPW>
__global__ __launch_bounds__(1024, 4) void snn_gemm_kernel(
    const _Float16* __restrict__ Wf, const _Float16* __restrict__ spk,
    _Float16* __restrict__ I)
{
    const int tid  = threadIdx.x;
    const int lane = tid & 63;
    const int w    = tid >> 6;            // wave 0..15
    const int quad = lane >> 4, mi = lane & 15;
    const int chunk = blockIdx.x % NC;
    const int nbb   = blockIdx.x / NC;
    const int row_base = nbb * 32;
    const int jcount = (200 - chunk + NC - 1) / NC;   // 16-m-tiles in chunk

    __shared__ _Float16 wlds[32 * 2048];              // 128 KB, A-frag order
    {   // contiguous copy: Wf 16-row groups 2*nbb, 2*nbb+1
        const half8_t* __restrict__ src = (const half8_t*)(Wf + (size_t)nbb * 65536);
        half8_t* __restrict__ dst = (half8_t*)wlds;
        #pragma unroll
        for (int r = 0; r < 8; ++r) dst[tid + r * 1024] = src[tid + r * 1024];
    }
    __syncthreads();

    for (int jl0 = TPW * w; jl0 < jcount; jl0 += 16 * TPW) {
        int mt[TPW]; bool val[TPW];
        const _Float16* bp[TPW];
        #pragma unroll
        for (int u = 0; u < TPW; ++u) {
            const int jl = jl0 + u;
            val[u] = jl < jcount;
            mt[u]  = chunk + NC * (val[u] ? jl : jl0);
            bp[u]  = spk + ((size_t)mt[u] * 16 + mi) * 8;
        }
        f32x4 acc[TPW][2];
        #pragma unroll
        for (int u = 0; u < TPW; ++u) { acc[u][0] = (f32x4){0,0,0,0}; acc[u][1] = (f32x4){0,0,0,0}; }

        half8_t bc[TPW];
        const size_t k0 = (size_t)quad * (MTOT * 8);
        #pragma unroll
        for (int u = 0; u < TPW; ++u) bc[u] = *(const half8_t*)(bp[u] + k0);

        #pragma unroll 4
        for (int kb = 0; kb < 64; ++kb) {
            half8_t bn[TPW];
            if (kb < 63) {
                const size_t kn = (size_t)((kb + 1) * 4 + quad) * (MTOT * 8);
                #pragma unroll
                for (int u = 0; u < TPW; ++u) bn[u] = *(const half8_t*)(bp[u] + kn);
            }
            const half8_t a0 = *(const half8_t*)(wlds + ((size_t)(kb * 64 + lane)) * 8);
            const half8_t a1 = *(const half8_t*)(wlds + 32768 + ((size_t)(kb * 64 + lane)) * 8);
            #pragma unroll
            for (int u = 0; u < TPW; ++u) {
                acc[u][0] = __builtin_amdgcn_mfma_f32_16x16x32_f16(a0, bc[u], acc[u][0], 0, 0, 0);
                acc[u][1] = __builtin_amdgcn_mfma_f32_16x16x32_f16(a1, bc[u], acc[u][1], 0, 0, 0);
            }
            #pragma unroll
            for (int u = 0; u < TPW; ++u) bc[u] = bn[u];
        }
        // store: C row(n)=quad*4+r, col(m)=mi -> octet-blocked I
        #pragma unroll
        for (int s = 0; s < 2; ++s) {
            const int n0 = row_base + s * 16 + quad * 4;
            const size_t obase = (size_t)(n0 >> 3) * (MTOT * 8) + (n0 & 7);
            #pragma unroll
            for (int u = 0; u < TPW; ++u) {
                if (!val[u]) continue;
                half4_t h;
                #pragma unroll
                for (int r = 0; r < 4; ++r) h[r] = (_Float16)acc[u][s][r];
                *(half4_t*)(I + obase + (size_t)(mt[u] * 16 + mi) * 8) = h;
            }
        }
    }
}

extern "C" void kernel_launch(void* const* d_in, const int* in_sizes, int n_in,
                              void* d_out, int out_size, void* d_ws, size_t ws_size,
                              hipStream_t stream) {
    // setup_inputs() dict order: x, noise, time_steps, W0, b0, W1, b1, W2, b2
    const float* x     = (const float*)d_in[0];
    const float* noise = (const float*)d_in[1];
    const float* W0 = (const float*)d_in[3];
    const float* b0 = (const float*)d_in[4];
    const float* W1 = (const float*)d_in[5];
    const float* b1 = (const float*)d_in[6];
    const float* W2 = (const float*)d_in[7];
    const float* b2 = (const float*)d_in[8];
    float* out = (float*)d_out;

    _Float16* R0 = (_Float16*)((char*)d_ws + R0_OFF);
    _Float16* R1 = (_Float16*)((char*)d_ws + R1_OFF);
    _Float16* Ib = (_Float16*)((char*)d_ws + I_OFF);

    // encode -> R0 ; convW0 -> R1
    snn_enc_convw_kernel<<<dim3(456), dim3(256), 0, stream>>>(x, noise, R0, out, W0, R1);
    // gemm0: 32 nbb x 8 chunks = 256 blocks (64-row, K-split pairs)
    snn_gemm64k_kernel<<<dim3(256), dim3(1024), 0, stream>>>(R1, R0, Ib);
    // scan0 (I->R1, 256 blocks) ; convW1 -> R0 (256 blocks)
    snn_scan_convw_kernel<<<dim3(512), dim3(256), 0, stream>>>(Ib, b0, R1, out, 256, 11, W1, R0);
    // gemm1
    snn_gemm64k_kernel<<<dim3(256), dim3(1024), 0, stream>>>(R0, R1, Ib);
    // scan1 (I->R0, 256 blocks) ; convW2 -> R1 (64 blocks)
    snn_scan_convw_kernel<<<dim3(320), dim3(256), 0, stream>>>(Ib, b1, R0, out, 256, 11, W2, R1);
    // gemm2: 16 nbb x 16 chunks = 256 blocks, 1 tile/wave (32-row, R9)
    snn_gemm_kernel<16, 1><<<dim3(256), dim3(1024), 0, stream>>>(R1, R0, Ib);
    // scan2 -> out
    snn_scan_kernel<<<dim3(64), dim3(256), 0, stream>>>(Ib, b2, out, 9);

    (void)in_sizes; (void)n_in; (void)out_size; (void)ws_size;
}

// Round 5
// 274.815 us; speedup vs baseline: 1.1318x; 1.1318x over previous
//
#include <hip/hip_runtime.h>

// SNN 2048->2048->2048->512, T=100, batch 32, LIF.
// Per layer: big GEMM over all t (M=3200=T*32) + sequential LIF scan.
// 7 stream-ordered launches, no grid sync.
//
// Unified "octet-blocked" layout (pitch MTOT) for spikes AND I:
//   half_idx(v, m) = ((v>>3)*MTOT + m)*8 + (v&7)     v = feature index
// Wave B-frag load at ((kb*4+quad)*MTOT + m0+mi)*8 yields
//   B[k=kb*32+quad*8+j][n=m0+mi]   (proven rounds 6-9).
//
// ws regions (total 39,321,600 B -- PROVEN available in round 7):
//   R0 [0,13107200) | R1 [+13107200) | I [+26214400)
// Schedule: fuse{enc->R0, convW0->R1} | gemm0(R1,R0->I) | fuse{scan0, convW1}
//   | gemm1 | fuse{scan1, convW2} | gemm2 | scan2(I->out)
//
// R14 (theory: latency-bound, single coupled 1024-thr block per CU defeats
// wave-level overlap -- R12/R13 refuted staging-drain & LDS-BW theories):
//   gemm64 -> 512-thread blocks, 64 KB LDS (one K-quarter of 64-row A),
//   2 INDEPENDENT blocks per CU. Grid 32 nbb x 8 chunks x 2 m-splits
//   = 512 blocks. Block computes 12|13 of its chunk's 25 m-tiles
//   (critical wave: 2 tiles = 512 MFMAs, same as R11). B-L2 ~420 MB
//   unchanged (R11's win preserved: each B-load feeds 4 MFMAs).
//   Staging: serial barrier-sandwiched global_load_lds x4 quarters
//   (drains overlap with the OTHER resident block's compute).
//   B prefetch: depth-2 named bE/bO, reload-after-use, zero copies.
#define T_STEPS 100
#define MTOT    3200
#define R0_OFF  0
#define R1_OFF  13107200
#define I_OFF   26214400

typedef _Float16 half8_t __attribute__((ext_vector_type(8)));
typedef _Float16 half4_t __attribute__((ext_vector_type(4)));
typedef float    f32x4   __attribute__((ext_vector_type(4)));

// ---------------- encode (device fn): Poisson spikes for all t ----------
__device__ __forceinline__ void encode_body(
    int blk, const float* __restrict__ x, const float* __restrict__ noise,
    _Float16* __restrict__ spk0, float* __restrict__ out)
{
    if (blk == 0 && threadIdx.x == 0) out[16384] = 0.0f;  // runs first
    const int tid = threadIdx.x;
    const int m0  = blk * 16;
    __shared__ half8_t lds[16 * 257];    // pad: store-phase reads conflict-free
    #pragma unroll
    for (int ml = 0; ml < 16; ++ml) {    // read phase: thread = feature octet
        const int m = m0 + ml;
        const int t = m >> 5, b = m & 31;
        const float4 x1 = *(const float4*)(x + b * 2048 + tid * 8);
        const float4 x2 = *(const float4*)(x + b * 2048 + tid * 8 + 4);
        const float4 n1 = *(const float4*)(noise + (size_t)t * 65536 + b * 2048 + tid * 8);
        const float4 n2 = *(const float4*)(noise + (size_t)t * 65536 + b * 2048 + tid * 8 + 4);
        const float xr[8] = {x1.x,x1.y,x1.z,x1.w,x2.x,x2.y,x2.z,x2.w};
        const float nz[8] = {n1.x,n1.y,n1.z,n1.w,n2.x,n2.y,n2.z,n2.w};
        half8_t sp;
        #pragma unroll
        for (int j = 0; j < 8; ++j) {
            const float r = fminf(fmaxf(xr[j], 0.0f), 1.0f);
            sp[j] = (nz[j] < r) ? (_Float16)1.0f : (_Float16)0.0f;
        }
        lds[ml * 257 + tid] = sp;
    }
    __syncthreads();
    #pragma unroll
    for (int r = 0; r < 16; ++r) {       // store phase: lanes = consecutive m
        const int ml  = tid & 15;
        const int oct = r * 16 + (tid >> 4);
        *(half8_t*)(spk0 + ((size_t)oct * MTOT + m0 + ml) * 8) = lds[ml * 257 + oct];
    }
}

// ------------- convw (device fn): W fp32 -> fp16 A-frag swizzled ---------
// Wf[(row>>4)*32768 + ((koct>>2)*64 + (koct&3)*16 + (row&15))*8 + j]
//   = W[row][koct*8+j];  8 rows per block.
__device__ __forceinline__ void convw_body(
    int blk, const float* __restrict__ W, _Float16* __restrict__ Wf)
{
    const int koct = threadIdx.x;        // 0..255
    #pragma unroll
    for (int r = 0; r < 8; ++r) {
        const int row = blk * 8 + r;
        const float* wp = W + (size_t)row * 2048 + koct * 8;
        const float4 f1 = *(const float4*)(wp);
        const float4 f2 = *(const float4*)(wp + 4);
        half8_t h = {(_Float16)f1.x,(_Float16)f1.y,(_Float16)f1.z,(_Float16)f1.w,
                     (_Float16)f2.x,(_Float16)f2.y,(_Float16)f2.z,(_Float16)f2.w};
        const size_t idx = (size_t)(row >> 4) * 32768
                         + ((size_t)((koct >> 2) * 64 + (koct & 3) * 16 + (row & 15))) * 8;
        *(half8_t*)(Wf + idx) = h;
    }
}

// ------------- scan (device fn): LIF, sequential t, parallel (n,b) -------
__device__ __forceinline__ void scan_body(
    int blk, const _Float16* __restrict__ I, const float* __restrict__ bias,
    _Float16* __restrict__ spk_out, float* __restrict__ out,
    const int nshift, const int is_last)
{
    const int gid = blk * 256 + threadIdx.x;     // [0, 32<<nshift)
    const int N = 1 << nshift;
    const int n = gid & (N - 1);
    const int b = gid >> nshift;
    const float bi = bias[n];
    const size_t nbase = (size_t)(n >> 3) * (MTOT * 8) + (n & 7);
    float mem = 0.f, syn = 0.f, osum = 0.f, cnt = 0.f;
    #pragma unroll 4
    for (int t = 0; t < T_STEPS; ++t) {
        const int m = t * 32 + b;
        const float Iv = (float)I[nbase + (size_t)m * 8] + bi;
        syn = syn + (-syn / 5.0f + Iv);
        mem = mem + (-mem / 20.0f + syn);
        const float sv = (mem >= 1.0f) ? 1.0f : 0.0f;
        mem = (sv != 0.0f) ? 0.0f : mem;       // reset
        mem = (mem > 0.0f) ? mem : 0.0f;       // clamp negatives
        cnt += sv; osum += sv;
        if (!is_last) spk_out[nbase + (size_t)m * 8] = (_Float16)sv;
    }
    if (is_last) out[b * 512 + n] = osum * 0.01f;    // mean over T
    float c = cnt;
    #pragma unroll
    for (int s2 = 1; s2 < 64; s2 <<= 1) c += __shfl_xor(c, s2);
    if ((threadIdx.x & 63) == 0) atomicAdd(&out[16384], c);
}

// ---------------- fused small kernels (all 256 thr) ----------------
__global__ __launch_bounds__(256, 2) void snn_enc_convw_kernel(
    const float* __restrict__ x, const float* __restrict__ noise,
    _Float16* __restrict__ spk0, float* __restrict__ out,
    const float* __restrict__ W, _Float16* __restrict__ Wf)
{
    if (blockIdx.x < 200) encode_body(blockIdx.x, x, noise, spk0, out);
    else                  convw_body(blockIdx.x - 200, W, Wf);
}

__global__ __launch_bounds__(256, 4) void snn_scan_convw_kernel(
    const _Float16* __restrict__ I, const float* __restrict__ bias,
    _Float16* __restrict__ spk_out, float* __restrict__ out,
    const int scan_blocks, const int nshift,
    const float* __restrict__ W, _Float16* __restrict__ Wf)
{
    if ((int)blockIdx.x < scan_blocks)
        scan_body(blockIdx.x, I, bias, spk_out, out, nshift, 0);
    else
        convw_body(blockIdx.x - scan_blocks, W, Wf);
}

__global__ __launch_bounds__(256, 4) void snn_scan_kernel(
    const _Float16* __restrict__ I, const float* __restrict__ bias,
    float* __restrict__ out, const int nshift)
{
    scan_body(blockIdx.x, I, bias, nullptr, out, nshift, 1);
}

// ========== 64-row GEMM, 512-thr / 2-per-CU (gemm0/1) ==========
// Block: 64 N-rows (4 A subtiles), 8 waves, 64 KB LDS = one K-quarter.
// Grid: 32 nbb x 8 chunks x 2 msl = 512 blocks; chunk == XCD (blk&7).
// msl=0 -> tiles jl 0..12 (13), msl=1 -> jl 13..24 (12) of the chunk's 25.
// Waves own {2,1} tiles (rem = jcount-8). Each B-load feeds 4|8 MFMAs.

__device__ __forceinline__ half8_t ldB(const _Float16* __restrict__ p, int kq) {
    return *(const half8_t*)(p + (size_t)kq * (MTOT * 8));
}

// Stage one 64 KB A-quarter (q = 0..3) via global_load_lds.
// unit = 16B; 4096 units = 4 row-groups x 1024. 8 insts/thread.
__device__ __forceinline__ void stage_q(
    const _Float16* __restrict__ Wf, _Float16* __restrict__ wlds,
    const int nbb, const int q, const int w, const int lane)
{
    #pragma unroll
    for (int r = 0; r < 8; ++r) {
        const int unit = r * 512 + w * 64 + lane;        // 0..4095
        const int s = unit >> 10, off = unit & 1023;     // group, intra
        const _Float16* src = Wf + (size_t)(4 * nbb + s) * 32768
                            + (size_t)q * 8192 + (size_t)off * 8;
        _Float16* dst = wlds + (size_t)unit * 8;
        __builtin_amdgcn_global_load_lds(
            (const __attribute__((address_space(1))) void*)src,
            (__attribute__((address_space(3))) void*)dst, 16, 0, 0);
    }
}

// One k-step: 4 A ds_reads feed 4|8 MFMAs; reload used B set <- kb+2.
template<bool HAS2>
__device__ __forceinline__ void kstep512(
    const _Float16* __restrict__ wlds, const _Float16* const (&bp)[2],
    half8_t (&bb)[2], f32x4 (&acc)[2][4],
    const int lane, const int quad, const int kb, const int j)
{
    half8_t a[4];
    #pragma unroll
    for (int s = 0; s < 4; ++s)
        a[s] = *(const half8_t*)(wlds + (size_t)s * 8192 + (size_t)(j * 64 + lane) * 8);
    #pragma unroll
    for (int s = 0; s < 4; ++s) {
        acc[0][s] = __builtin_amdgcn_mfma_f32_16x16x32_f16(a[s], bb[0], acc[0][s], 0, 0, 0);
        if (HAS2)
            acc[1][s] = __builtin_amdgcn_mfma_f32_16x16x32_f16(a[s], bb[1], acc[1][s], 0, 0, 0);
    }
    if (kb + 2 < 64) {                 // depth-2: reload for kb+2
        const int kq = (kb + 2) * 4 + quad;
        bb[0] = ldB(bp[0], kq);
        if (HAS2) bb[1] = ldB(bp[1], kq);
    }
}

template<bool HAS2>
__device__ __forceinline__ void gemm64s_run(
    const _Float16* __restrict__ Wf, const _Float16* __restrict__ spk,
    _Float16* __restrict__ I, _Float16* __restrict__ wlds,
    const int (&mt)[2], const int nbb, const int row_base,
    const int w, const int lane, const int quad, const int mi)
{
    const _Float16* bp[2];
    bp[0] = spk + ((size_t)mt[0] * 16 + mi) * 8;
    bp[1] = spk + ((size_t)mt[1] * 16 + mi) * 8;

    // B preload kb=0,1 FIRST (oldest in vmcnt order): the stage drain at
    // the first __syncthreads completes them for free.
    half8_t bE[2], bO[2];
    bE[0] = ldB(bp[0], quad);
    bO[0] = ldB(bp[0], 4 + quad);
    if (HAS2) { bE[1] = ldB(bp[1], quad); bO[1] = ldB(bp[1], 4 + quad); }

    stage_q(Wf, wlds, nbb, 0, w, lane);
    __syncthreads();

    f32x4 acc[2][4];
    #pragma unroll
    for (int u = 0; u < 2; ++u) {
        #pragma unroll
        for (int s = 0; s < 4; ++s) acc[u][s] = (f32x4){0, 0, 0, 0};
    }

    #pragma unroll 1
    for (int q = 0; q < 4; ++q) {
        #pragma unroll
        for (int j = 0; j < 16; j += 2) {
            kstep512<HAS2>(wlds, bp, bE, acc, lane, quad, q * 16 + j,     j);
            kstep512<HAS2>(wlds, bp, bO, acc, lane, quad, q * 16 + j + 1, j + 1);
        }
        __syncthreads();                        // all reads of quarter done
        if (q < 3) {
            stage_q(Wf, wlds, nbb, q + 1, w, lane);
            __syncthreads();                    // quarter q+1 resident
        }
    }

    // store: C row(n)=quad*4+r within subtile s, col(m)=mi -> octet-blocked I
    #pragma unroll
    for (int s = 0; s < 4; ++s) {
        const int n0 = row_base + s * 16 + quad * 4;
        const size_t obase = (size_t)(n0 >> 3) * (MTOT * 8) + (n0 & 7);
        #pragma unroll
        for (int u = 0; u < 2; ++u) {
            if (u == 1 && !HAS2) continue;
            half4_t h;
            #pragma unroll
            for (int r = 0; r < 4; ++r) h[r] = (_Float16)acc[u][s][r];
            *(half4_t*)(I + obase + (size_t)(mt[u] * 16 + mi) * 8) = h;
        }
    }
}

__global__ __launch_bounds__(512, 4) void snn_gemm64s_kernel(
    const _Float16* __restrict__ Wf, const _Float16* __restrict__ spk,
    _Float16* __restrict__ I)
{
    const int tid  = threadIdx.x;
    const int lane = tid & 63;
    const int w    = tid >> 6;            // wave 0..7
    const int mi   = lane & 15;
    const int quad = lane >> 4;
    const int chunk = blockIdx.x & 7;          // == XCD
    const int msl   = (blockIdx.x >> 3) & 1;   // m-split half
    const int nbb   = blockIdx.x >> 4;         // 0..31 (64-row groups)
    const int row_base = nbb * 64;
    const int jbase  = msl ? 13 : 0;
    const int jcount = msl ? 12 : 13;
    const int rem    = jcount - 8;        // waves w<rem own 2 tiles
    const bool has2  = (w < rem);
    const int jl_start = jbase + (has2 ? 2 * w : w + rem);

    int mt[2];
    #pragma unroll
    for (int u = 0; u < 2; ++u) {
        int jl = jl_start + u;
        if (jl >= jbase + jcount) jl = jbase + jcount - 1;  // clamp unused
        mt[u] = chunk + 8 * jl;
    }

    __shared__ _Float16 wlds[32768];      // 64 KB: one K-quarter of A

    if (has2) gemm64s_run<true >(Wf, spk, I, wlds, mt, nbb, row_base, w, lane, quad, mi);
    else      gemm64s_run<false>(Wf, spk, I, wlds, mt, nbb, row_base, w, lane, quad, mi);
}

// ============== 32-row GEMM (gemm2, proven R9 version) ==================
template<int NC, int TPW>
__global__ __launch_bounds__(1024, 4) void snn_gemm_kernel(
    const _Float16* __restrict__ Wf, const _Float16* __restrict__ spk,
    _Float16* __restrict__ I)
{
    const int tid  = threadIdx.x;
    const int lane = tid & 63;
    const int w    = tid >> 6;            // wave 0..15
    const int quad = lane >> 4, mi = lane & 15;
    const int chunk = blockIdx.x % NC;
    const int nbb   = blockIdx.x / NC;
    const int row_base = nbb * 32;
    const int jcount = (200 - chunk + NC - 1) / NC;   // 16-m-tiles in chunk

    __shared__ _Float16 wlds[32 * 2048];              // 128 KB, A-frag order
    {   // contiguous copy: Wf 16-row groups 2*nbb, 2*nbb+1
        const half8_t* __restrict__ src = (const half8_t*)(Wf + (size_t)nbb * 65536);
        half8_t* __restrict__ dst = (half8_t*)wlds;
        #pragma unroll
        for (int r = 0; r < 8; ++r) dst[tid + r * 1024] = src[tid + r * 1024];
    }
    __syncthreads();

    for (int jl0 = TPW * w; jl0 < jcount; jl0 += 16 * TPW) {
        int mt[TPW]; bool val[TPW];
        const _Float16* bp[TPW];
        #pragma unroll
        for (int u = 0; u < TPW; ++u) {
            const int jl = jl0 + u;
            val[u] = jl < jcount;
            mt[u]  = chunk + NC * (val[u] ? jl : jl0);
            bp[u]  = spk + ((size_t)mt[u] * 16 + mi) * 8;
        }
        f32x4 acc[TPW][2];
        #pragma unroll
        for (int u = 0; u < TPW; ++u) { acc[u][0] = (f32x4){0,0,0,0}; acc[u][1] = (f32x4){0,0,0,0}; }

        half8_t bc[TPW];
        const size_t k0 = (size_t)quad * (MTOT * 8);
        #pragma unroll
        for (int u = 0; u < TPW; ++u) bc[u] = *(const half8_t*)(bp[u] + k0);

        #pragma unroll 4
        for (int kb = 0; kb < 64; ++kb) {
            half8_t bn[TPW];
            if (kb < 63) {
                const size_t kn = (size_t)((kb + 1) * 4 + quad) * (MTOT * 8);
                #pragma unroll
                for (int u = 0; u < TPW; ++u) bn[u] = *(const half8_t*)(bp[u] + kn);
            }
            const half8_t a0 = *(const half8_t*)(wlds + ((size_t)(kb * 64 + lane)) * 8);
            const half8_t a1 = *(const half8_t*)(wlds + 32768 + ((size_t)(kb * 64 + lane)) * 8);
            #pragma unroll
            for (int u = 0; u < TPW; ++u) {
                acc[u][0] = __builtin_amdgcn_mfma_f32_16x16x32_f16(a0, bc[u], acc[u][0], 0, 0, 0);
                acc[u][1] = __builtin_amdgcn_mfma_f32_16x16x32_f16(a1, bc[u], acc[u][1], 0, 0, 0);
            }
            #pragma unroll
            for (int u = 0; u < TPW; ++u) bc[u] = bn[u];
        }
        // store: C row(n)=quad*4+r, col(m)=mi -> octet-blocked I
        #pragma unroll
        for (int s = 0; s < 2; ++s) {
            const int n0 = row_base + s * 16 + quad * 4;
            const size_t obase = (size_t)(n0 >> 3) * (MTOT * 8) + (n0 & 7);
            #pragma unroll
            for (int u = 0; u < TPW; ++u) {
                if (!val[u]) continue;
                half4_t h;
                #pragma unroll
                for (int r = 0; r < 4; ++r) h[r] = (_Float16)acc[u][s][r];
                *(half4_t*)(I + obase + (size_t)(mt[u] * 16 + mi) * 8) = h;
            }
        }
    }
}

extern "C" void kernel_launch(void* const* d_in, const int* in_sizes, int n_in,
                              void* d_out, int out_size, void* d_ws, size_t ws_size,
                              hipStream_t stream) {
    // setup_inputs() dict order: x, noise, time_steps, W0, b0, W1, b1, W2, b2
    const float* x     = (const float*)d_in[0];
    const float* noise = (const float*)d_in[1];
    const float* W0 = (const float*)d_in[3];
    const float* b0 = (const float*)d_in[4];
    const float* W1 = (const float*)d_in[5];
    const float* b1 = (const float*)d_in[6];
    const float* W2 = (const float*)d_in[7];
    const float* b2 = (const float*)d_in[8];
    float* out = (float*)d_out;

    _Float16* R0 = (_Float16*)((char*)d_ws + R0_OFF);
    _Float16* R1 = (_Float16*)((char*)d_ws + R1_OFF);
    _Float16* Ib = (_Float16*)((char*)d_ws + I_OFF);

    // encode -> R0 ; convW0 -> R1
    snn_enc_convw_kernel<<<dim3(456), dim3(256), 0, stream>>>(x, noise, R0, out, W0, R1);
    // gemm0: 32 nbb x 8 chunks x 2 msl = 512 blocks (64-row, 512 thr)
    snn_gemm64s_kernel<<<dim3(512), dim3(512), 0, stream>>>(R1, R0, Ib);
    // scan0 (I->R1, 256 blocks) ; convW1 -> R0 (256 blocks)
    snn_scan_convw_kernel<<<dim3(512), dim3(256), 0, stream>>>(Ib, b0, R1, out, 256, 11, W1, R0);
    // gemm1
    snn_gemm64s_kernel<<<dim3(512), dim3(512), 0, stream>>>(R0, R1, Ib);
    // scan1 (I->R0, 256 blocks) ; convW2 -> R1 (64 blocks)
    snn_scan_convw_kernel<<<dim3(320), dim3(256), 0, stream>>>(Ib, b1, R0, out, 256, 11, W2, R1);
    // gemm2: 16 nbb x 16 chunks = 256 blocks, 1 tile/wave (32-row, R9)
    snn_gemm_kernel<16, 1><<<dim3(256), dim3(1024), 0, stream>>>(R1, R0, Ib);
    // scan2 -> out
    snn_scan_kernel<<<dim3(64), dim3(256), 0, stream>>>(Ib, b2, out, 9);

    (void)in_sizes; (void)n_in; (void)out_size; (void)ws_size;
}

// Round 6
// 274.007 us; speedup vs baseline: 1.1351x; 1.0029x over previous
//
#include <hip/hip_runtime.h>

// SNN 2048->2048->2048->512, T=100, batch 32, LIF.
// Per layer: big GEMM over all t (M=3200=T*32) + sequential LIF scan.
// 7 stream-ordered launches, no grid sync.
//
// Unified "octet-blocked" layout (pitch MTOT) for spikes AND I:
//   half_idx(v, m) = ((v>>3)*MTOT + m)*8 + (v&7)     v = feature index
// Wave B-frag load at ((kb*4+quad)*MTOT + m0+mi)*8 yields
//   B[k=kb*32+quad*8+j][n=m0+mi]   (proven rounds 6-9).
//
// ws regions (total 39,321,600 B -- PROVEN available in round 7):
//   R0 [0,13107200) | R1 [+13107200) | I [+26214400)
// Schedule: fuse{enc->R0, convW0->R1} | gemm0(R1,R0->I) | fuse{scan0, convW1}
//   | gemm1 | fuse{scan1, convW2} | gemm2 | scan2(I->out)
//
// R15 (theory: scan over-fetch 4x -- old lane map read 8 scattered 16B
// chunks per wave per t; fills wipe caches each iter so it's cold HBM):
//   - scan thread remap: j=gid&7, b=(gid>>3)&31, oct=gid>>8. Wave reads
//     128B CONTIGUOUS per t (block: 512B/t streamed). Bijective, nbase
//     formula unchanged -> layout-identical, pure coalescing fix.
//   - gemm2 -> 64-row TLP structure (template NCHUNK=16): 8nbb x 16chunks
//     x 2msl = 256 blocks; each B-load feeds 4 MFMAs (B-L2 218->109MB).
//     Store-guard for tile-less waves (jcount<8); barrier flow uniform.
//   - gemm0/1 path identical to R14 (NCHUNK=8).
#define T_STEPS 100
#define MTOT    3200
#define R0_OFF  0
#define R1_OFF  13107200
#define I_OFF   26214400

typedef _Float16 half8_t __attribute__((ext_vector_type(8)));
typedef _Float16 half4_t __attribute__((ext_vector_type(4)));
typedef float    f32x4   __attribute__((ext_vector_type(4)));

// ---------------- encode (device fn): Poisson spikes for all t ----------
__device__ __forceinline__ void encode_body(
    int blk, const float* __restrict__ x, const float* __restrict__ noise,
    _Float16* __restrict__ spk0, float* __restrict__ out)
{
    if (blk == 0 && threadIdx.x == 0) out[16384] = 0.0f;  // runs first
    const int tid = threadIdx.x;
    const int m0  = blk * 16;
    __shared__ half8_t lds[16 * 257];    // pad: store-phase reads conflict-free
    #pragma unroll
    for (int ml = 0; ml < 16; ++ml) {    // read phase: thread = feature octet
        const int m = m0 + ml;
        const int t = m >> 5, b = m & 31;
        const float4 x1 = *(const float4*)(x + b * 2048 + tid * 8);
        const float4 x2 = *(const float4*)(x + b * 2048 + tid * 8 + 4);
        const float4 n1 = *(const float4*)(noise + (size_t)t * 65536 + b * 2048 + tid * 8);
        const float4 n2 = *(const float4*)(noise + (size_t)t * 65536 + b * 2048 + tid * 8 + 4);
        const float xr[8] = {x1.x,x1.y,x1.z,x1.w,x2.x,x2.y,x2.z,x2.w};
        const float nz[8] = {n1.x,n1.y,n1.z,n1.w,n2.x,n2.y,n2.z,n2.w};
        half8_t sp;
        #pragma unroll
        for (int j = 0; j < 8; ++j) {
            const float r = fminf(fmaxf(xr[j], 0.0f), 1.0f);
            sp[j] = (nz[j] < r) ? (_Float16)1.0f : (_Float16)0.0f;
        }
        lds[ml * 257 + tid] = sp;
    }
    __syncthreads();
    #pragma unroll
    for (int r = 0; r < 16; ++r) {       // store phase: lanes = consecutive m
        const int ml  = tid & 15;
        const int oct = r * 16 + (tid >> 4);
        *(half8_t*)(spk0 + ((size_t)oct * MTOT + m0 + ml) * 8) = lds[ml * 257 + oct];
    }
}

// ------------- convw (device fn): W fp32 -> fp16 A-frag swizzled ---------
// Wf[(row>>4)*32768 + ((koct>>2)*64 + (koct&3)*16 + (row&15))*8 + j]
//   = W[row][koct*8+j];  8 rows per block.
__device__ __forceinline__ void convw_body(
    int blk, const float* __restrict__ W, _Float16* __restrict__ Wf)
{
    const int koct = threadIdx.x;        // 0..255
    #pragma unroll
    for (int r = 0; r < 8; ++r) {
        const int row = blk * 8 + r;
        const float* wp = W + (size_t)row * 2048 + koct * 8;
        const float4 f1 = *(const float4*)(wp);
        const float4 f2 = *(const float4*)(wp + 4);
        half8_t h = {(_Float16)f1.x,(_Float16)f1.y,(_Float16)f1.z,(_Float16)f1.w,
                     (_Float16)f2.x,(_Float16)f2.y,(_Float16)f2.z,(_Float16)f2.w};
        const size_t idx = (size_t)(row >> 4) * 32768
                         + ((size_t)((koct >> 2) * 64 + (koct & 3) * 16 + (row & 15))) * 8;
        *(half8_t*)(Wf + idx) = h;
    }
}

// ------------- scan (device fn): LIF, sequential t, parallel (n,b) -------
// R15 remap: j=gid&7, b=(gid>>3)&31, oct=gid>>8. Wave = one octet x b 0..7
// -> per-t loads/stores are 128B contiguous per wave (512B per block).
__device__ __forceinline__ void scan_body(
    int blk, const _Float16* __restrict__ I, const float* __restrict__ bias,
    _Float16* __restrict__ spk_out, float* __restrict__ out,
    const int nshift, const int is_last)
{
    const int gid = blk * 256 + threadIdx.x;
    const int j   = gid & 7;            // intra-octet feature
    const int b   = (gid >> 3) & 31;    // batch
    const int oct = gid >> 8;           // feature octet (block == octet)
    const int n   = oct * 8 + j;
    const float bi = bias[n];
    const size_t nbase = (size_t)oct * (MTOT * 8) + j;
    float mem = 0.f, syn = 0.f, osum = 0.f, cnt = 0.f;
    #pragma unroll 4
    for (int t = 0; t < T_STEPS; ++t) {
        const int m = t * 32 + b;
        const float Iv = (float)I[nbase + (size_t)m * 8] + bi;
        syn = syn + (-syn / 5.0f + Iv);
        mem = mem + (-mem / 20.0f + syn);
        const float sv = (mem >= 1.0f) ? 1.0f : 0.0f;
        mem = (sv != 0.0f) ? 0.0f : mem;       // reset
        mem = (mem > 0.0f) ? mem : 0.0f;       // clamp negatives
        cnt += sv; osum += sv;
        if (!is_last) spk_out[nbase + (size_t)m * 8] = (_Float16)sv;
    }
    if (is_last) out[b * 512 + n] = osum * 0.01f;    // mean over T
    float c = cnt;
    #pragma unroll
    for (int s2 = 1; s2 < 64; s2 <<= 1) c += __shfl_xor(c, s2);
    if ((threadIdx.x & 63) == 0) atomicAdd(&out[16384], c);
    (void)nshift;
}

// ---------------- fused small kernels (all 256 thr) ----------------
__global__ __launch_bounds__(256, 2) void snn_enc_convw_kernel(
    const float* __restrict__ x, const float* __restrict__ noise,
    _Float16* __restrict__ spk0, float* __restrict__ out,
    const float* __restrict__ W, _Float16* __restrict__ Wf)
{
    if (blockIdx.x < 200) encode_body(blockIdx.x, x, noise, spk0, out);
    else                  convw_body(blockIdx.x - 200, W, Wf);
}

__global__ __launch_bounds__(256, 4) void snn_scan_convw_kernel(
    const _Float16* __restrict__ I, const float* __restrict__ bias,
    _Float16* __restrict__ spk_out, float* __restrict__ out,
    const int scan_blocks, const int nshift,
    const float* __restrict__ W, _Float16* __restrict__ Wf)
{
    if ((int)blockIdx.x < scan_blocks)
        scan_body(blockIdx.x, I, bias, spk_out, out, nshift, 0);
    else
        convw_body(blockIdx.x - scan_blocks, W, Wf);
}

__global__ __launch_bounds__(256, 4) void snn_scan_kernel(
    const _Float16* __restrict__ I, const float* __restrict__ bias,
    float* __restrict__ out, const int nshift)
{
    scan_body(blockIdx.x, I, bias, nullptr, out, nshift, 1);
}

// ========== 64-row GEMM, 512-thr, templated chunks (gemm0/1/2) ==========
// Block: 64 N-rows (4 A subtiles), 8 waves, 64 KB LDS = one K-quarter.
// Grid: NBB x NCHUNK x 2 msl blocks. NCHUNK=8: chunk == XCD; jt=25,
// msl {13,12}, waves own {2,1} tiles. NCHUNK=16 (gemm2): jt=12|13,
// msl {7|6,6}, waves own {1,0} tiles (tile-less waves compute clamped
// tile, skip store; barrier flow uniform).

__device__ __forceinline__ half8_t ldB(const _Float16* __restrict__ p, int kq) {
    return *(const half8_t*)(p + (size_t)kq * (MTOT * 8));
}

// Stage one 64 KB A-quarter (q = 0..3) via global_load_lds.
// unit = 16B; 4096 units = 4 row-groups x 1024. 8 insts/thread.
__device__ __forceinline__ void stage_q(
    const _Float16* __restrict__ Wf, _Float16* __restrict__ wlds,
    const int nbb, const int q, const int w, const int lane)
{
    #pragma unroll
    for (int r = 0; r < 8; ++r) {
        const int unit = r * 512 + w * 64 + lane;        // 0..4095
        const int s = unit >> 10, off = unit & 1023;     // group, intra
        const _Float16* src = Wf + (size_t)(4 * nbb + s) * 32768
                            + (size_t)q * 8192 + (size_t)off * 8;
        _Float16* dst = wlds + (size_t)unit * 8;
        __builtin_amdgcn_global_load_lds(
            (const __attribute__((address_space(1))) void*)src,
            (__attribute__((address_space(3))) void*)dst, 16, 0, 0);
    }
}

// One k-step: 4 A ds_reads feed 4|8 MFMAs; reload used B set <- kb+2.
template<bool HAS2>
__device__ __forceinline__ void kstep512(
    const _Float16* __restrict__ wlds, const _Float16* const (&bp)[2],
    half8_t (&bb)[2], f32x4 (&acc)[2][4],
    const int lane, const int quad, const int kb, const int j)
{
    half8_t a[4];
    #pragma unroll
    for (int s = 0; s < 4; ++s)
        a[s] = *(const half8_t*)(wlds + (size_t)s * 8192 + (size_t)(j * 64 + lane) * 8);
    #pragma unroll
    for (int s = 0; s < 4; ++s) {
        acc[0][s] = __builtin_amdgcn_mfma_f32_16x16x32_f16(a[s], bb[0], acc[0][s], 0, 0, 0);
        if (HAS2)
            acc[1][s] = __builtin_amdgcn_mfma_f32_16x16x32_f16(a[s], bb[1], acc[1][s], 0, 0, 0);
    }
    if (kb + 2 < 64) {                 // depth-2: reload for kb+2
        const int kq = (kb + 2) * 4 + quad;
        bb[0] = ldB(bp[0], kq);
        if (HAS2) bb[1] = ldB(bp[1], kq);
    }
}

template<bool HAS2>
__device__ __forceinline__ void gemm64s_run(
    const _Float16* __restrict__ Wf, const _Float16* __restrict__ spk,
    _Float16* __restrict__ I, _Float16* __restrict__ wlds,
    const int (&mt)[2], const int nbb, const int row_base,
    const int w, const int lane, const int quad, const int mi,
    const bool st)
{
    const _Float16* bp[2];
    bp[0] = spk + ((size_t)mt[0] * 16 + mi) * 8;
    bp[1] = spk + ((size_t)mt[1] * 16 + mi) * 8;

    // B preload kb=0,1 FIRST (oldest in vmcnt order): the stage drain at
    // the first __syncthreads completes them for free.
    half8_t bE[2], bO[2];
    bE[0] = ldB(bp[0], quad);
    bO[0] = ldB(bp[0], 4 + quad);
    if (HAS2) { bE[1] = ldB(bp[1], quad); bO[1] = ldB(bp[1], 4 + quad); }

    stage_q(Wf, wlds, nbb, 0, w, lane);
    __syncthreads();

    f32x4 acc[2][4];
    #pragma unroll
    for (int u = 0; u < 2; ++u) {
        #pragma unroll
        for (int s = 0; s < 4; ++s) acc[u][s] = (f32x4){0, 0, 0, 0};
    }

    #pragma unroll 1
    for (int q = 0; q < 4; ++q) {
        #pragma unroll
        for (int j = 0; j < 16; j += 2) {
            kstep512<HAS2>(wlds, bp, bE, acc, lane, quad, q * 16 + j,     j);
            kstep512<HAS2>(wlds, bp, bO, acc, lane, quad, q * 16 + j + 1, j + 1);
        }
        __syncthreads();                        // all reads of quarter done
        if (q < 3) {
            stage_q(Wf, wlds, nbb, q + 1, w, lane);
            __syncthreads();                    // quarter q+1 resident
        }
    }

    // store: C row(n)=quad*4+r within subtile s, col(m)=mi -> octet-blocked I
    #pragma unroll
    for (int s = 0; s < 4; ++s) {
        const int n0 = row_base + s * 16 + quad * 4;
        const size_t obase = (size_t)(n0 >> 3) * (MTOT * 8) + (n0 & 7);
        #pragma unroll
        for (int u = 0; u < 2; ++u) {
            if (u == 0 && !st) continue;
            if (u == 1 && !HAS2) continue;
            half4_t h;
            #pragma unroll
            for (int r = 0; r < 4; ++r) h[r] = (_Float16)acc[u][s][r];
            *(half4_t*)(I + obase + (size_t)(mt[u] * 16 + mi) * 8) = h;
        }
    }
}

template<int NCHUNK>
__global__ __launch_bounds__(512, 4) void snn_gemm64s_kernel(
    const _Float16* __restrict__ Wf, const _Float16* __restrict__ spk,
    _Float16* __restrict__ I)
{
    const int tid  = threadIdx.x;
    const int lane = tid & 63;
    const int w    = tid >> 6;            // wave 0..7
    const int mi   = lane & 15;
    const int quad = lane >> 4;
    const int chunk = blockIdx.x % NCHUNK;
    const int rest  = blockIdx.x / NCHUNK;
    const int msl   = rest & 1;           // m-split half
    const int nbb   = rest >> 1;          // 64-row group
    const int row_base = nbb * 64;
    const int jt     = (200 - chunk + NCHUNK - 1) / NCHUNK;  // chunk tiles
    const int jh     = (jt + 1) >> 1;
    const int jbase  = msl ? jh : 0;
    const int jcount = msl ? (jt - jh) : jh;
    const int rem    = jcount - 8;        // >0: waves w<rem own 2 tiles
    const bool has2  = (w < rem);
    const int r2     = rem > 0 ? rem : 0;
    const bool st    = has2 || (w + r2) < jcount;   // wave has a tile
    int jl_start = jbase + (has2 ? 2 * w : w + r2);
    const int jmax = jbase + jcount - 1;
    if (jl_start > jmax) jl_start = jmax;           // clamp tile-less waves

    int mt[2];
    #pragma unroll
    for (int u = 0; u < 2; ++u) {
        int jl = jl_start + u;
        if (jl > jmax) jl = jmax;                   // clamp unused slot
        mt[u] = chunk + NCHUNK * jl;
    }

    __shared__ _Float16 wlds[32768];      // 64 KB: one K-quarter of A

    if (has2) gemm64s_run<true >(Wf, spk, I, wlds, mt, nbb, row_base, w, lane, quad, mi, true);
    else      gemm64s_run<false>(Wf, spk, I, wlds, mt, nbb, row_base, w, lane, quad, mi, st);
}

extern "C" void kernel_launch(void* const* d_in, const int* in_sizes, int n_in,
                              void* d_out, int out_size, void* d_ws, size_t ws_size,
                              hipStream_t stream) {
    // setup_inputs() dict order: x, noise, time_steps, W0, b0, W1, b1, W2, b2
    const float* x     = (const float*)d_in[0];
    const float* noise = (const float*)d_in[1];
    const float* W0 = (const float*)d_in[3];
    const float* b0 = (const float*)d_in[4];
    const float* W1 = (const float*)d_in[5];
    const float* b1 = (const float*)d_in[6];
    const float* W2 = (const float*)d_in[7];
    const float* b2 = (const float*)d_in[8];
    float* out = (float*)d_out;

    _Float16* R0 = (_Float16*)((char*)d_ws + R0_OFF);
    _Float16* R1 = (_Float16*)((char*)d_ws + R1_OFF);
    _Float16* Ib = (_Float16*)((char*)d_ws + I_OFF);

    // encode -> R0 ; convW0 -> R1
    snn_enc_convw_kernel<<<dim3(456), dim3(256), 0, stream>>>(x, noise, R0, out, W0, R1);
    // gemm0: 32 nbb x 8 chunks x 2 msl = 512 blocks (64-row, 512 thr)
    snn_gemm64s_kernel<8><<<dim3(512), dim3(512), 0, stream>>>(R1, R0, Ib);
    // scan0 (I->R1, 256 octet-blocks) ; convW1 -> R0 (256 blocks)
    snn_scan_convw_kernel<<<dim3(512), dim3(256), 0, stream>>>(Ib, b0, R1, out, 256, 11, W1, R0);
    // gemm1
    snn_gemm64s_kernel<8><<<dim3(512), dim3(512), 0, stream>>>(R0, R1, Ib);
    // scan1 (I->R0, 256 octet-blocks) ; convW2 -> R1 (64 blocks)
    snn_scan_convw_kernel<<<dim3(320), dim3(256), 0, stream>>>(Ib, b1, R0, out, 256, 11, W2, R1);
    // gemm2: 8 nbb x 16 chunks x 2 msl = 256 blocks (64-row, 512 thr)
    snn_gemm64s_kernel<16><<<dim3(256), dim3(512), 0, stream>>>(R1, R0, Ib);
    // scan2 -> out (64 octet-blocks)
    snn_scan_kernel<<<dim3(64), dim3(256), 0, stream>>>(Ib, b2, out, 9);

    (void)in_sizes; (void)n_in; (void)out_size; (void)ws_size;
}

// Round 7
// 273.419 us; speedup vs baseline: 1.1376x; 1.0022x over previous
//
#include <hip/hip_runtime.h>
#include <hip/hip_cooperative_groups.h>

// SNN 2048->2048->2048->512, T=100, batch 32, LIF.
// R16: ONE cooperative mega-kernel (512 blocks x 512 thr x 64KB LDS =
// exactly 2 blocks/CU co-resident), 6 grid.sync() phase boundaries --
// removes all inter-kernel launch/drain overhead and makes the pipeline
// a single rocprof-visible dispatch. Legacy 7-launch path kept as a
// runtime fallback if occupancy check fails.
//
// Unified "octet-blocked" layout (pitch MTOT) for spikes AND I:
//   half_idx(v, m) = ((v>>3)*MTOT + m)*8 + (v&7)
// ws regions: R0 [0,13107200) | R1 [+13107200) | I [+26214400)
// Phases: E{enc->R0, convW0->R1} | G0 gemm(R1,R0->I) | S0{scan I->R1,
//   convW1->R0} | G1 | S1{scan I->R0, convW2->R1} | G2(256 blk) | S2->out
#define T_STEPS 100
#define MTOT    3200
#define R0_OFF  0
#define R1_OFF  13107200
#define I_OFF   26214400

typedef _Float16 half8_t __attribute__((ext_vector_type(8)));
typedef _Float16 half4_t __attribute__((ext_vector_type(4)));
typedef float    f32x4   __attribute__((ext_vector_type(4)));

// ============ encode, 512-thr, 64KB XOR-swizzled LDS ====================
// Block handles 16 m. koct = tid&255 (feature octet), mlh = tid>>8.
// LDS [16][256] half8, col ^= ml: write conflict-free (consecutive koct),
// read 2-way max (free). Exactly 64 KB (fits 2 blocks/CU).
__device__ __forceinline__ void encode512_body(
    int blk, const float* __restrict__ x, const float* __restrict__ noise,
    _Float16* __restrict__ spk0, float* __restrict__ out, _Float16* smem)
{
    if (blk == 0 && threadIdx.x == 0) out[16384] = 0.0f;  // runs first
    const int tid  = threadIdx.x;
    const int m0   = blk * 16;
    const int koct = tid & 255;
    const int mlh  = tid >> 8;
    half8_t* lds = (half8_t*)smem;       // [16][256]
    #pragma unroll
    for (int mlq = 0; mlq < 8; ++mlq) {
        const int ml = mlq * 2 + mlh;
        const int m  = m0 + ml;
        const int t = m >> 5, b = m & 31;
        const float4 x1 = *(const float4*)(x + b * 2048 + koct * 8);
        const float4 x2 = *(const float4*)(x + b * 2048 + koct * 8 + 4);
        const float4 n1 = *(const float4*)(noise + (size_t)t * 65536 + b * 2048 + koct * 8);
        const float4 n2 = *(const float4*)(noise + (size_t)t * 65536 + b * 2048 + koct * 8 + 4);
        const float xr[8] = {x1.x,x1.y,x1.z,x1.w,x2.x,x2.y,x2.z,x2.w};
        const float nz[8] = {n1.x,n1.y,n1.z,n1.w,n2.x,n2.y,n2.z,n2.w};
        half8_t sp;
        #pragma unroll
        for (int q = 0; q < 8; ++q) {
            const float r = fminf(fmaxf(xr[q], 0.0f), 1.0f);
            sp[q] = (nz[q] < r) ? (_Float16)1.0f : (_Float16)0.0f;
        }
        lds[ml * 256 + (koct ^ ml)] = sp;
    }
    __syncthreads();
    #pragma unroll
    for (int r = 0; r < 8; ++r) {        // lanes: ml fast -> 256B contiguous
        const int ml  = tid & 15;
        const int oct = r * 32 + (tid >> 4);
        *(half8_t*)(spk0 + ((size_t)oct * MTOT + m0 + ml) * 8)
            = lds[ml * 256 + (oct ^ ml)];
    }
}

// ============ convw, 512-thr: W fp32 -> fp16 A-frag swizzled ============
// Wf[(row>>4)*32768 + ((koct>>2)*64 + (koct&3)*16 + (row&15))*8 + j]
//   = W[row][koct*8+j];  16 rows per block (koct=tid&255, rh=tid>>8).
__device__ __forceinline__ void convw512_body(
    int cblk, const float* __restrict__ W, _Float16* __restrict__ Wf)
{
    const int koct = threadIdx.x & 255;
    const int rh   = threadIdx.x >> 8;
    #pragma unroll
    for (int r = 0; r < 8; ++r) {
        const int row = cblk * 16 + rh * 8 + r;
        const float* wp = W + (size_t)row * 2048 + koct * 8;
        const float4 f1 = *(const float4*)(wp);
        const float4 f2 = *(const float4*)(wp + 4);
        half8_t h = {(_Float16)f1.x,(_Float16)f1.y,(_Float16)f1.z,(_Float16)f1.w,
                     (_Float16)f2.x,(_Float16)f2.y,(_Float16)f2.z,(_Float16)f2.w};
        const size_t idx = (size_t)(row >> 4) * 32768
                         + ((size_t)((koct >> 2) * 64 + (koct & 3) * 16 + (row & 15))) * 8;
        *(half8_t*)(Wf + idx) = h;
    }
}

// ============ scan, 512-thr (R15 coalesced remap) =======================
// gid = blk*512+tid: j=gid&7, b=(gid>>3)&31, oct=gid>>8. Wave reads/writes
// 128B contiguous per t.
__device__ __forceinline__ void scan512_body(
    int blk, const _Float16* __restrict__ I, const float* __restrict__ bias,
    _Float16* __restrict__ spk_out, float* __restrict__ out, const int is_last)
{
    const int gid = blk * 512 + threadIdx.x;
    const int j   = gid & 7;
    const int b   = (gid >> 3) & 31;
    const int oct = gid >> 8;
    const int n   = oct * 8 + j;
    const float bi = bias[n];
    const size_t nbase = (size_t)oct * (MTOT * 8) + j;
    float mem = 0.f, syn = 0.f, osum = 0.f, cnt = 0.f;
    #pragma unroll 4
    for (int t = 0; t < T_STEPS; ++t) {
        const int m = t * 32 + b;
        const float Iv = (float)I[nbase + (size_t)m * 8] + bi;
        syn = syn + (-syn / 5.0f + Iv);
        mem = mem + (-mem / 20.0f + syn);
        const float sv = (mem >= 1.0f) ? 1.0f : 0.0f;
        mem = (sv != 0.0f) ? 0.0f : mem;       // reset
        mem = (mem > 0.0f) ? mem : 0.0f;       // clamp negatives
        cnt += sv; osum += sv;
        if (!is_last) spk_out[nbase + (size_t)m * 8] = (_Float16)sv;
    }
    if (is_last) out[b * 512 + n] = osum * 0.01f;    // mean over T
    float c = cnt;
    #pragma unroll
    for (int s2 = 1; s2 < 64; s2 <<= 1) c += __shfl_xor(c, s2);
    if ((threadIdx.x & 63) == 0) atomicAdd(&out[16384], c);
}

// ============ 64-row GEMM body (proven R14/R15 structure) ===============
__device__ __forceinline__ half8_t ldB(const _Float16* __restrict__ p, int kq) {
    return *(const half8_t*)(p + (size_t)kq * (MTOT * 8));
}

__device__ __forceinline__ void stage_q(
    const _Float16* __restrict__ Wf, _Float16* __restrict__ wlds,
    const int nbb, const int q, const int w, const int lane)
{
    #pragma unroll
    for (int r = 0; r < 8; ++r) {
        const int unit = r * 512 + w * 64 + lane;        // 0..4095 (16B)
        const int s = unit >> 10, off = unit & 1023;
        const _Float16* src = Wf + (size_t)(4 * nbb + s) * 32768
                            + (size_t)q * 8192 + (size_t)off * 8;
        _Float16* dst = wlds + (size_t)unit * 8;
        __builtin_amdgcn_global_load_lds(
            (const __attribute__((address_space(1))) void*)src,
            (__attribute__((address_space(3))) void*)dst, 16, 0, 0);
    }
}

template<bool HAS2>
__device__ __forceinline__ void kstep512(
    const _Float16* __restrict__ wlds, const _Float16* const (&bp)[2],
    half8_t (&bb)[2], f32x4 (&acc)[2][4],
    const int lane, const int quad, const int kb, const int j)
{
    half8_t a[4];
    #pragma unroll
    for (int s = 0; s < 4; ++s)
        a[s] = *(const half8_t*)(wlds + (size_t)s * 8192 + (size_t)(j * 64 + lane) * 8);
    #pragma unroll
    for (int s = 0; s < 4; ++s) {
        acc[0][s] = __builtin_amdgcn_mfma_f32_16x16x32_f16(a[s], bb[0], acc[0][s], 0, 0, 0);
        if (HAS2)
            acc[1][s] = __builtin_amdgcn_mfma_f32_16x16x32_f16(a[s], bb[1], acc[1][s], 0, 0, 0);
    }
    if (kb + 2 < 64) {                 // depth-2: reload for kb+2
        const int kq = (kb + 2) * 4 + quad;
        bb[0] = ldB(bp[0], kq);
        if (HAS2) bb[1] = ldB(bp[1], kq);
    }
}

template<bool HAS2>
__device__ __forceinline__ void gemm64s_run(
    const _Float16* __restrict__ Wf, const _Float16* __restrict__ spk,
    _Float16* __restrict__ I, _Float16* __restrict__ wlds,
    const int (&mt)[2], const int nbb, const int row_base,
    const int w, const int lane, const int quad, const int mi,
    const bool st)
{
    const _Float16* bp[2];
    bp[0] = spk + ((size_t)mt[0] * 16 + mi) * 8;
    bp[1] = spk + ((size_t)mt[1] * 16 + mi) * 8;

    half8_t bE[2], bO[2];
    bE[0] = ldB(bp[0], quad);
    bO[0] = ldB(bp[0], 4 + quad);
    if (HAS2) { bE[1] = ldB(bp[1], quad); bO[1] = ldB(bp[1], 4 + quad); }

    stage_q(Wf, wlds, nbb, 0, w, lane);
    __syncthreads();

    f32x4 acc[2][4];
    #pragma unroll
    for (int u = 0; u < 2; ++u) {
        #pragma unroll
        for (int s = 0; s < 4; ++s) acc[u][s] = (f32x4){0, 0, 0, 0};
    }

    #pragma unroll 1
    for (int q = 0; q < 4; ++q) {
        #pragma unroll
        for (int j = 0; j < 16; j += 2) {
            kstep512<HAS2>(wlds, bp, bE, acc, lane, quad, q * 16 + j,     j);
            kstep512<HAS2>(wlds, bp, bO, acc, lane, quad, q * 16 + j + 1, j + 1);
        }
        __syncthreads();
        if (q < 3) {
            stage_q(Wf, wlds, nbb, q + 1, w, lane);
            __syncthreads();
        }
    }

    #pragma unroll
    for (int s = 0; s < 4; ++s) {
        const int n0 = row_base + s * 16 + quad * 4;
        const size_t obase = (size_t)(n0 >> 3) * (MTOT * 8) + (n0 & 7);
        #pragma unroll
        for (int u = 0; u < 2; ++u) {
            if (u == 0 && !st) continue;
            if (u == 1 && !HAS2) continue;
            half4_t h;
            #pragma unroll
            for (int r = 0; r < 4; ++r) h[r] = (_Float16)acc[u][s][r];
            *(half4_t*)(I + obase + (size_t)(mt[u] * 16 + mi) * 8) = h;
        }
    }
}

template<int NCHUNK>
__device__ __forceinline__ void gemm64s_body(
    const int bid, const _Float16* __restrict__ Wf,
    const _Float16* __restrict__ spk, _Float16* __restrict__ I,
    _Float16* __restrict__ wlds)
{
    const int tid  = threadIdx.x;
    const int lane = tid & 63;
    const int w    = tid >> 6;            // wave 0..7
    const int mi   = lane & 15;
    const int quad = lane >> 4;
    const int chunk = bid % NCHUNK;
    const int rest  = bid / NCHUNK;
    const int msl   = rest & 1;
    const int nbb   = rest >> 1;
    const int row_base = nbb * 64;
    const int jt     = (200 - chunk + NCHUNK - 1) / NCHUNK;
    const int jh     = (jt + 1) >> 1;
    const int jbase  = msl ? jh : 0;
    const int jcount = msl ? (jt - jh) : jh;
    const int rem    = jcount - 8;
    const bool has2  = (w < rem);
    const int r2     = rem > 0 ? rem : 0;
    const bool st    = has2 || (w + r2) < jcount;
    int jl_start = jbase + (has2 ? 2 * w : w + r2);
    const int jmax = jbase + jcount - 1;
    if (jl_start > jmax) jl_start = jmax;

    int mt[2];
    #pragma unroll
    for (int u = 0; u < 2; ++u) {
        int jl = jl_start + u;
        if (jl > jmax) jl = jmax;
        mt[u] = chunk + NCHUNK * jl;
    }

    if (has2) gemm64s_run<true >(Wf, spk, I, wlds, mt, nbb, row_base, w, lane, quad, mi, true);
    else      gemm64s_run<false>(Wf, spk, I, wlds, mt, nbb, row_base, w, lane, quad, mi, st);
}

// ==================== THE MEGA KERNEL (cooperative) =====================
__global__ __launch_bounds__(512, 4) void snn_mega_kernel(
    const float* __restrict__ x, const float* __restrict__ noise,
    const float* __restrict__ W0, const float* __restrict__ b0,
    const float* __restrict__ W1, const float* __restrict__ b1,
    const float* __restrict__ W2, const float* __restrict__ b2,
    _Float16* __restrict__ R0, _Float16* __restrict__ R1,
    _Float16* __restrict__ Ib, float* __restrict__ out)
{
    cooperative_groups::grid_group grid = cooperative_groups::this_grid();
    __shared__ _Float16 smem[32768];          // 64 KB, reused each phase
    const int blk = blockIdx.x;               // 0..511

    // E: encode -> R0 (200 blks) ; convW0 -> R1 (128 blks)
    if (blk < 200)      encode512_body(blk, x, noise, R0, out, smem);
    else if (blk < 328) convw512_body(blk - 200, W0, R1);
    grid.sync();
    // G0: gemm0(R1, R0 -> I), all 512 blocks
    gemm64s_body<8>(blk, R1, R0, Ib, smem);
    grid.sync();
    // S0: scan0 I->R1 (128 blks) ; convW1 -> R0 (128 blks)
    if (blk < 128)      scan512_body(blk, Ib, b0, R1, out, 0);
    else if (blk < 256) convw512_body(blk - 128, W1, R0);
    grid.sync();
    // G1: gemm1(R0, R1 -> I)
    gemm64s_body<8>(blk, R0, R1, Ib, smem);
    grid.sync();
    // S1: scan1 I->R0 (128 blks) ; convW2 -> R1 (32 blks)
    if (blk < 128)      scan512_body(blk, Ib, b1, R0, out, 0);
    else if (blk < 160) convw512_body(blk - 128, W2, R1);
    grid.sync();
    // G2: gemm2(R1, R0 -> I), 256 blocks
    if (blk < 256) gemm64s_body<16>(blk, R1, R0, Ib, smem);
    grid.sync();
    // S2: scan2 -> out (32 blks)
    if (blk < 32) scan512_body(blk, Ib, b2, nullptr, out, 1);
}

// =================== legacy kernels (fallback path) =====================
__global__ __launch_bounds__(512, 4) void snn_enc512_kernel(
    const float* __restrict__ x, const float* __restrict__ noise,
    _Float16* __restrict__ spk0, float* __restrict__ out,
    const float* __restrict__ W, _Float16* __restrict__ Wf)
{
    __shared__ _Float16 smem[32768];
    if (blockIdx.x < 200) encode512_body(blockIdx.x, x, noise, spk0, out, smem);
    else                  convw512_body(blockIdx.x - 200, W, Wf);
}

__global__ __launch_bounds__(512, 4) void snn_scan_convw512_kernel(
    const _Float16* __restrict__ I, const float* __restrict__ bias,
    _Float16* __restrict__ spk_out, float* __restrict__ out,
    const int scan_blocks, const float* __restrict__ W,
    _Float16* __restrict__ Wf)
{
    if ((int)blockIdx.x < scan_blocks)
        scan512_body(blockIdx.x, I, bias, spk_out, out, 0);
    else
        convw512_body(blockIdx.x - scan_blocks, W, Wf);
}

__global__ __launch_bounds__(512, 4) void snn_scan512_kernel(
    const _Float16* __restrict__ I, const float* __restrict__ bias,
    float* __restrict__ out)
{
    scan512_body(blockIdx.x, I, bias, nullptr, out, 1);
}

template<int NCHUNK>
__global__ __launch_bounds__(512, 4) void snn_gemm64s_kernel(
    const _Float16* __restrict__ Wf, const _Float16* __restrict__ spk,
    _Float16* __restrict__ I)
{
    __shared__ _Float16 wlds[32768];
    gemm64s_body<NCHUNK>(blockIdx.x, Wf, spk, I, wlds);
}

extern "C" void kernel_launch(void* const* d_in, const int* in_sizes, int n_in,
                              void* d_out, int out_size, void* d_ws, size_t ws_size,
                              hipStream_t stream) {
    // setup_inputs() dict order: x, noise, time_steps, W0, b0, W1, b1, W2, b2
    const float* x     = (const float*)d_in[0];
    const float* noise = (const float*)d_in[1];
    const float* W0 = (const float*)d_in[3];
    const float* b0 = (const float*)d_in[4];
    const float* W1 = (const float*)d_in[5];
    const float* b1 = (const float*)d_in[6];
    const float* W2 = (const float*)d_in[7];
    const float* b2 = (const float*)d_in[8];
    float* out = (float*)d_out;

    _Float16* R0 = (_Float16*)((char*)d_ws + R0_OFF);
    _Float16* R1 = (_Float16*)((char*)d_ws + R1_OFF);
    _Float16* Ib = (_Float16*)((char*)d_ws + I_OFF);

    // Cooperative-capable? Need 2 blocks/CU (512 blocks co-resident).
    int maxb = 0;
    hipError_t oe = hipOccupancyMaxActiveBlocksPerMultiprocessor(
        &maxb, (const void*)snn_mega_kernel, 512, 0);

    if (oe == hipSuccess && maxb >= 2) {
        void* args[] = {(void*)&x, (void*)&noise,
                        (void*)&W0, (void*)&b0, (void*)&W1, (void*)&b1,
                        (void*)&W2, (void*)&b2,
                        (void*)&R0, (void*)&R1, (void*)&Ib, (void*)&out};
        hipLaunchCooperativeKernel((const void*)snn_mega_kernel,
                                   dim3(512), dim3(512), args, 0, stream);
    } else {
        // Legacy 7-launch path (R15-equivalent, proven 274 us)
        snn_enc512_kernel<<<dim3(328), dim3(512), 0, stream>>>(x, noise, R0, out, W0, R1);
        snn_gemm64s_kernel<8><<<dim3(512), dim3(512), 0, stream>>>(R1, R0, Ib);
        snn_scan_convw512_kernel<<<dim3(256), dim3(512), 0, stream>>>(Ib, b0, R1, out, 128, W1, R0);
        snn_gemm64s_kernel<8><<<dim3(512), dim3(512), 0, stream>>>(R0, R1, Ib);
        snn_scan_convw512_kernel<<<dim3(160), dim3(512), 0, stream>>>(Ib, b1, R0, out, 128, W2, R1);
        snn_gemm64s_kernel<16><<<dim3(256), dim3(512), 0, stream>>>(R1, R0, Ib);
        snn_scan512_kernel<<<dim3(32), dim3(512), 0, stream>>>(Ib, b2, out);
    }

    (void)in_sizes; (void)n_in; (void)out_size; (void)ws_size;
}

// Round 8
// 245.653 us; speedup vs baseline: 1.2661x; 1.1130x over previous
//
#include <hip/hip_runtime.h>
#include <hip/hip_cooperative_groups.h>

// SNN 2048->2048->2048->512, T=100, batch 32, LIF.
// R17 = R16 mega-kernel (one cooperative launch, 512 blk x 512 thr x
// 64KB LDS = 2 blocks/CU, 6 grid.sync) + two targeted fixes:
//  1) G12 atomic fix: scan's per-WAVE atomicAdd to the single spike
//     counter (1024 same-address device-scope RMWs per scan phase,
//     strictly serialized) -> per-BLOCK LDS reduction, ONE atomic/block
//     (2304 -> 288 atomics total).
//  2) GEMM B prefetch depth 2 -> 4 (named sets b0..b3, reload<-kb+4,
//     zero copies). VGPR 60 -> ~80, still 2 blocks/CU.
//
// Unified "octet-blocked" layout (pitch MTOT) for spikes AND I:
//   half_idx(v, m) = ((v>>3)*MTOT + m)*8 + (v&7)
// ws regions: R0 [0,13107200) | R1 [+13107200) | I [+26214400)
// Phases: E{enc->R0, convW0->R1} | G0 gemm(R1,R0->I) | S0{scan I->R1,
//   convW1->R0} | G1 | S1{scan I->R0, convW2->R1} | G2(256 blk) | S2->out
#define T_STEPS 100
#define MTOT    3200
#define R0_OFF  0
#define R1_OFF  13107200
#define I_OFF   26214400

typedef _Float16 half8_t __attribute__((ext_vector_type(8)));
typedef _Float16 half4_t __attribute__((ext_vector_type(4)));
typedef float    f32x4   __attribute__((ext_vector_type(4)));

// ============ encode, 512-thr, 64KB XOR-swizzled LDS ====================
__device__ __forceinline__ void encode512_body(
    int blk, const float* __restrict__ x, const float* __restrict__ noise,
    _Float16* __restrict__ spk0, float* __restrict__ out, _Float16* smem)
{
    if (blk == 0 && threadIdx.x == 0) out[16384] = 0.0f;  // runs first
    const int tid  = threadIdx.x;
    const int m0   = blk * 16;
    const int koct = tid & 255;
    const int mlh  = tid >> 8;
    half8_t* lds = (half8_t*)smem;       // [16][256]
    #pragma unroll
    for (int mlq = 0; mlq < 8; ++mlq) {
        const int ml = mlq * 2 + mlh;
        const int m  = m0 + ml;
        const int t = m >> 5, b = m & 31;
        const float4 x1 = *(const float4*)(x + b * 2048 + koct * 8);
        const float4 x2 = *(const float4*)(x + b * 2048 + koct * 8 + 4);
        const float4 n1 = *(const float4*)(noise + (size_t)t * 65536 + b * 2048 + koct * 8);
        const float4 n2 = *(const float4*)(noise + (size_t)t * 65536 + b * 2048 + koct * 8 + 4);
        const float xr[8] = {x1.x,x1.y,x1.z,x1.w,x2.x,x2.y,x2.z,x2.w};
        const float nz[8] = {n1.x,n1.y,n1.z,n1.w,n2.x,n2.y,n2.z,n2.w};
        half8_t sp;
        #pragma unroll
        for (int q = 0; q < 8; ++q) {
            const float r = fminf(fmaxf(xr[q], 0.0f), 1.0f);
            sp[q] = (nz[q] < r) ? (_Float16)1.0f : (_Float16)0.0f;
        }
        lds[ml * 256 + (koct ^ ml)] = sp;
    }
    __syncthreads();
    #pragma unroll
    for (int r = 0; r < 8; ++r) {        // lanes: ml fast -> 256B contiguous
        const int ml  = tid & 15;
        const int oct = r * 32 + (tid >> 4);
        *(half8_t*)(spk0 + ((size_t)oct * MTOT + m0 + ml) * 8)
            = lds[ml * 256 + (oct ^ ml)];
    }
}

// ============ convw, 512-thr: W fp32 -> fp16 A-frag swizzled ============
__device__ __forceinline__ void convw512_body(
    int cblk, const float* __restrict__ W, _Float16* __restrict__ Wf)
{
    const int koct = threadIdx.x & 255;
    const int rh   = threadIdx.x >> 8;
    #pragma unroll
    for (int r = 0; r < 8; ++r) {
        const int row = cblk * 16 + rh * 8 + r;
        const float* wp = W + (size_t)row * 2048 + koct * 8;
        const float4 f1 = *(const float4*)(wp);
        const float4 f2 = *(const float4*)(wp + 4);
        half8_t h = {(_Float16)f1.x,(_Float16)f1.y,(_Float16)f1.z,(_Float16)f1.w,
                     (_Float16)f2.x,(_Float16)f2.y,(_Float16)f2.z,(_Float16)f2.w};
        const size_t idx = (size_t)(row >> 4) * 32768
                         + ((size_t)((koct >> 2) * 64 + (koct & 3) * 16 + (row & 15))) * 8;
        *(half8_t*)(Wf + idx) = h;
    }
}

// ============ scan, 512-thr, per-BLOCK single atomic (R17) ==============
// gid mapping (R15 coalesced): j=gid&7, b=(gid>>3)&31, oct=gid>>8.
// rsum: 8-float scratch (reuses phase-dead smem in the mega kernel).
__device__ __forceinline__ void scan512_body(
    int blk, const _Float16* __restrict__ I, const float* __restrict__ bias,
    _Float16* __restrict__ spk_out, float* __restrict__ out,
    const int is_last, float* rsum)
{
    const int gid = blk * 512 + threadIdx.x;
    const int j   = gid & 7;
    const int b   = (gid >> 3) & 31;
    const int oct = gid >> 8;
    const int n   = oct * 8 + j;
    const float bi = bias[n];
    const size_t nbase = (size_t)oct * (MTOT * 8) + j;
    float mem = 0.f, syn = 0.f, osum = 0.f, cnt = 0.f;
    #pragma unroll 4
    for (int t = 0; t < T_STEPS; ++t) {
        const int m = t * 32 + b;
        const float Iv = (float)I[nbase + (size_t)m * 8] + bi;
        syn = syn + (-syn / 5.0f + Iv);
        mem = mem + (-mem / 20.0f + syn);
        const float sv = (mem >= 1.0f) ? 1.0f : 0.0f;
        mem = (sv != 0.0f) ? 0.0f : mem;       // reset
        mem = (mem > 0.0f) ? mem : 0.0f;       // clamp negatives
        cnt += sv; osum += sv;
        if (!is_last) spk_out[nbase + (size_t)m * 8] = (_Float16)sv;
    }
    if (is_last) out[b * 512 + n] = osum * 0.01f;    // mean over T
    // wave reduce -> LDS -> one atomic per block (G12; was one per wave)
    float c = cnt;
    #pragma unroll
    for (int s2 = 1; s2 < 64; s2 <<= 1) c += __shfl_xor(c, s2);
    const int wid = threadIdx.x >> 6;
    if ((threadIdx.x & 63) == 0) rsum[wid] = c;
    __syncthreads();
    if (threadIdx.x == 0) {
        float s = rsum[0];
        #pragma unroll
        for (int ww = 1; ww < 8; ++ww) s += rsum[ww];
        atomicAdd(&out[16384], s);
    }
    __syncthreads();   // rsum dead before smem reuse
}

// ============ 64-row GEMM body (R14 structure + depth-4 B) ==============
__device__ __forceinline__ half8_t ldB(const _Float16* __restrict__ p, int kq) {
    return *(const half8_t*)(p + (size_t)kq * (MTOT * 8));
}

__device__ __forceinline__ void stage_q(
    const _Float16* __restrict__ Wf, _Float16* __restrict__ wlds,
    const int nbb, const int q, const int w, const int lane)
{
    #pragma unroll
    for (int r = 0; r < 8; ++r) {
        const int unit = r * 512 + w * 64 + lane;        // 0..4095 (16B)
        const int s = unit >> 10, off = unit & 1023;
        const _Float16* src = Wf + (size_t)(4 * nbb + s) * 32768
                            + (size_t)q * 8192 + (size_t)off * 8;
        _Float16* dst = wlds + (size_t)unit * 8;
        __builtin_amdgcn_global_load_lds(
            (const __attribute__((address_space(1))) void*)src,
            (__attribute__((address_space(3))) void*)dst, 16, 0, 0);
    }
}

// One k-step: 4 A ds_reads feed 4|8 MFMAs; reload used B set <- kb+4.
template<bool HAS2>
__device__ __forceinline__ void kstep512(
    const _Float16* __restrict__ wlds, const _Float16* const (&bp)[2],
    half8_t (&bb)[2], f32x4 (&acc)[2][4],
    const int lane, const int quad, const int kb, const int j)
{
    half8_t a[4];
    #pragma unroll
    for (int s = 0; s < 4; ++s)
        a[s] = *(const half8_t*)(wlds + (size_t)s * 8192 + (size_t)(j * 64 + lane) * 8);
    #pragma unroll
    for (int s = 0; s < 4; ++s) {
        acc[0][s] = __builtin_amdgcn_mfma_f32_16x16x32_f16(a[s], bb[0], acc[0][s], 0, 0, 0);
        if (HAS2)
            acc[1][s] = __builtin_amdgcn_mfma_f32_16x16x32_f16(a[s], bb[1], acc[1][s], 0, 0, 0);
    }
    if (kb + 4 < 64) {                 // depth-4: reload for kb+4
        const int kq = (kb + 4) * 4 + quad;
        bb[0] = ldB(bp[0], kq);
        if (HAS2) bb[1] = ldB(bp[1], kq);
    }
}

template<bool HAS2>
__device__ __forceinline__ void gemm64s_run(
    const _Float16* __restrict__ Wf, const _Float16* __restrict__ spk,
    _Float16* __restrict__ I, _Float16* __restrict__ wlds,
    const int (&mt)[2], const int nbb, const int row_base,
    const int w, const int lane, const int quad, const int mi,
    const bool st)
{
    const _Float16* bp[2];
    bp[0] = spk + ((size_t)mt[0] * 16 + mi) * 8;
    bp[1] = spk + ((size_t)mt[1] * 16 + mi) * 8;

    // depth-4 B preload kb=0..3 FIRST (oldest in vmcnt order): the stage
    // drain at the first __syncthreads completes them for free.
    half8_t B0[2], B1[2], B2[2], B3[2];
    B0[0] = ldB(bp[0],      quad);
    B1[0] = ldB(bp[0],  4 + quad);
    B2[0] = ldB(bp[0],  8 + quad);
    B3[0] = ldB(bp[0], 12 + quad);
    if (HAS2) {
        B0[1] = ldB(bp[1],      quad);
        B1[1] = ldB(bp[1],  4 + quad);
        B2[1] = ldB(bp[1],  8 + quad);
        B3[1] = ldB(bp[1], 12 + quad);
    }

    stage_q(Wf, wlds, nbb, 0, w, lane);
    __syncthreads();

    f32x4 acc[2][4];
    #pragma unroll
    for (int u = 0; u < 2; ++u) {
        #pragma unroll
        for (int s = 0; s < 4; ++s) acc[u][s] = (f32x4){0, 0, 0, 0};
    }

    #pragma unroll 1
    for (int q = 0; q < 4; ++q) {
        #pragma unroll
        for (int j = 0; j < 16; j += 4) {
            kstep512<HAS2>(wlds, bp, B0, acc, lane, quad, q * 16 + j,     j);
            kstep512<HAS2>(wlds, bp, B1, acc, lane, quad, q * 16 + j + 1, j + 1);
            kstep512<HAS2>(wlds, bp, B2, acc, lane, quad, q * 16 + j + 2, j + 2);
            kstep512<HAS2>(wlds, bp, B3, acc, lane, quad, q * 16 + j + 3, j + 3);
        }
        __syncthreads();
        if (q < 3) {
            stage_q(Wf, wlds, nbb, q + 1, w, lane);
            __syncthreads();
        }
    }

    #pragma unroll
    for (int s = 0; s < 4; ++s) {
        const int n0 = row_base + s * 16 + quad * 4;
        const size_t obase = (size_t)(n0 >> 3) * (MTOT * 8) + (n0 & 7);
        #pragma unroll
        for (int u = 0; u < 2; ++u) {
            if (u == 0 && !st) continue;
            if (u == 1 && !HAS2) continue;
            half4_t h;
            #pragma unroll
            for (int r = 0; r < 4; ++r) h[r] = (_Float16)acc[u][s][r];
            *(half4_t*)(I + obase + (size_t)(mt[u] * 16 + mi) * 8) = h;
        }
    }
}

template<int NCHUNK>
__device__ __forceinline__ void gemm64s_body(
    const int bid, const _Float16* __restrict__ Wf,
    const _Float16* __restrict__ spk, _Float16* __restrict__ I,
    _Float16* __restrict__ wlds)
{
    const int tid  = threadIdx.x;
    const int lane = tid & 63;
    const int w    = tid >> 6;            // wave 0..7
    const int mi   = lane & 15;
    const int quad = lane >> 4;
    const int chunk = bid % NCHUNK;
    const int rest  = bid / NCHUNK;
    const int msl   = rest & 1;
    const int nbb   = rest >> 1;
    const int row_base = nbb * 64;
    const int jt     = (200 - chunk + NCHUNK - 1) / NCHUNK;
    const int jh     = (jt + 1) >> 1;
    const int jbase  = msl ? jh : 0;
    const int jcount = msl ? (jt - jh) : jh;
    const int rem    = jcount - 8;
    const bool has2  = (w < rem);
    const int r2     = rem > 0 ? rem : 0;
    const bool st    = has2 || (w + r2) < jcount;
    int jl_start = jbase + (has2 ? 2 * w : w + r2);
    const int jmax = jbase + jcount - 1;
    if (jl_start > jmax) jl_start = jmax;

    int mt[2];
    #pragma unroll
    for (int u = 0; u < 2; ++u) {
        int jl = jl_start + u;
        if (jl > jmax) jl = jmax;
        mt[u] = chunk + NCHUNK * jl;
    }

    if (has2) gemm64s_run<true >(Wf, spk, I, wlds, mt, nbb, row_base, w, lane, quad, mi, true);
    else      gemm64s_run<false>(Wf, spk, I, wlds, mt, nbb, row_base, w, lane, quad, mi, st);
}

// ==================== THE MEGA KERNEL (cooperative) =====================
__global__ __launch_bounds__(512, 4) void snn_mega_kernel(
    const float* __restrict__ x, const float* __restrict__ noise,
    const float* __restrict__ W0, const float* __restrict__ b0,
    const float* __restrict__ W1, const float* __restrict__ b1,
    const float* __restrict__ W2, const float* __restrict__ b2,
    _Float16* __restrict__ R0, _Float16* __restrict__ R1,
    _Float16* __restrict__ Ib, float* __restrict__ out)
{
    cooperative_groups::grid_group grid = cooperative_groups::this_grid();
    __shared__ _Float16 smem[32768];          // 64 KB, reused each phase
    const int blk = blockIdx.x;               // 0..511

    // E: encode -> R0 (200 blks) ; convW0 -> R1 (128 blks)
    if (blk < 200)      encode512_body(blk, x, noise, R0, out, smem);
    else if (blk < 328) convw512_body(blk - 200, W0, R1);
    grid.sync();
    // G0: gemm0(R1, R0 -> I), all 512 blocks
    gemm64s_body<8>(blk, R1, R0, Ib, smem);
    grid.sync();
    // S0: scan0 I->R1 (128 blks) ; convW1 -> R0 (128 blks)
    if (blk < 128)      scan512_body(blk, Ib, b0, R1, out, 0, (float*)smem);
    else if (blk < 256) convw512_body(blk - 128, W1, R0);
    grid.sync();
    // G1: gemm1(R0, R1 -> I)
    gemm64s_body<8>(blk, R0, R1, Ib, smem);
    grid.sync();
    // S1: scan1 I->R0 (128 blks) ; convW2 -> R1 (32 blks)
    if (blk < 128)      scan512_body(blk, Ib, b1, R0, out, 0, (float*)smem);
    else if (blk < 160) convw512_body(blk - 128, W2, R1);
    grid.sync();
    // G2: gemm2(R1, R0 -> I), 256 blocks
    if (blk < 256) gemm64s_body<16>(blk, R1, R0, Ib, smem);
    grid.sync();
    // S2: scan2 -> out (32 blks)
    if (blk < 32) scan512_body(blk, Ib, b2, nullptr, out, 1, (float*)smem);
}

// =================== legacy kernels (fallback path) =====================
__global__ __launch_bounds__(512, 4) void snn_enc512_kernel(
    const float* __restrict__ x, const float* __restrict__ noise,
    _Float16* __restrict__ spk0, float* __restrict__ out,
    const float* __restrict__ W, _Float16* __restrict__ Wf)
{
    __shared__ _Float16 smem[32768];
    if (blockIdx.x < 200) encode512_body(blockIdx.x, x, noise, spk0, out, smem);
    else                  convw512_body(blockIdx.x - 200, W, Wf);
}

__global__ __launch_bounds__(512, 4) void snn_scan_convw512_kernel(
    const _Float16* __restrict__ I, const float* __restrict__ bias,
    _Float16* __restrict__ spk_out, float* __restrict__ out,
    const int scan_blocks, const float* __restrict__ W,
    _Float16* __restrict__ Wf)
{
    __shared__ float rsum[8];
    if ((int)blockIdx.x < scan_blocks)
        scan512_body(blockIdx.x, I, bias, spk_out, out, 0, rsum);
    else
        convw512_body(blockIdx.x - scan_blocks, W, Wf);
}

__global__ __launch_bounds__(512, 4) void snn_scan512_kernel(
    const _Float16* __restrict__ I, const float* __restrict__ bias,
    float* __restrict__ out)
{
    __shared__ float rsum[8];
    scan512_body(blockIdx.x, I, bias, nullptr, out, 1, rsum);
}

template<int NCHUNK>
__global__ __launch_bounds__(512, 4) void snn_gemm64s_kernel(
    const _Float16* __restrict__ Wf, const _Float16* __restrict__ spk,
    _Float16* __restrict__ I)
{
    __shared__ _Float16 wlds[32768];
    gemm64s_body<NCHUNK>(blockIdx.x, Wf, spk, I, wlds);
}

extern "C" void kernel_launch(void* const* d_in, const int* in_sizes, int n_in,
                              void* d_out, int out_size, void* d_ws, size_t ws_size,
                              hipStream_t stream) {
    // setup_inputs() dict order: x, noise, time_steps, W0, b0, W1, b1, W2, b2
    const float* x     = (const float*)d_in[0];
    const float* noise = (const float*)d_in[1];
    const float* W0 = (const float*)d_in[3];
    const float* b0 = (const float*)d_in[4];
    const float* W1 = (const float*)d_in[5];
    const float* b1 = (const float*)d_in[6];
    const float* W2 = (const float*)d_in[7];
    const float* b2 = (const float*)d_in[8];
    float* out = (float*)d_out;

    _Float16* R0 = (_Float16*)((char*)d_ws + R0_OFF);
    _Float16* R1 = (_Float16*)((char*)d_ws + R1_OFF);
    _Float16* Ib = (_Float16*)((char*)d_ws + I_OFF);

    // Cooperative-capable? Need 2 blocks/CU (512 blocks co-resident).
    int maxb = 0;
    hipError_t oe = hipOccupancyMaxActiveBlocksPerMultiprocessor(
        &maxb, (const void*)snn_mega_kernel, 512, 0);

    if (oe == hipSuccess && maxb >= 2) {
        void* args[] = {(void*)&x, (void*)&noise,
                        (void*)&W0, (void*)&b0, (void*)&W1, (void*)&b1,
                        (void*)&W2, (void*)&b2,
                        (void*)&R0, (void*)&R1, (void*)&Ib, (void*)&out};
        hipLaunchCooperativeKernel((const void*)snn_mega_kernel,
                                   dim3(512), dim3(512), args, 0, stream);
    } else {
        // Legacy 7-launch path
        snn_enc512_kernel<<<dim3(328), dim3(512), 0, stream>>>(x, noise, R0, out, W0, R1);
        snn_gemm64s_kernel<8><<<dim3(512), dim3(512), 0, stream>>>(R1, R0, Ib);
        snn_scan_convw512_kernel<<<dim3(256), dim3(512), 0, stream>>>(Ib, b0, R1, out, 128, W1, R0);
        snn_gemm64s_kernel<8><<<dim3(512), dim3(512), 0, stream>>>(R0, R1, Ib);
        snn_scan_convw512_kernel<<<dim3(160), dim3(512), 0, stream>>>(Ib, b1, R0, out, 128, W2, R1);
        snn_gemm64s_kernel<16><<<dim3(256), dim3(512), 0, stream>>>(R1, R0, Ib);
        snn_scan512_kernel<<<dim3(32), dim3(512), 0, stream>>>(Ib, b2, out);
    }

    (void)in_sizes; (void)n_in; (void)out_size; (void)ws_size;
}